// Round 2
// baseline (922.239 us; speedup 1.0000x reference)
//
#include <hip/hip_runtime.h>
#include <math.h>

// AnswerPointerNetwork: H=256, B=64, LP=2048, LQ=64, fp32 in/out.
// R7 (resubmit — prior run died to container-acquire infra failure):
//  (1) A staged to LDS as bf16 via registers (global f32x4 -> cvt8 ->
//      ds_write_b128). LDS 48KB -> 32KB per block: occupancy 3 -> 4-5
//      blocks/CU. MFMA already consumed A as bf16, so numerics unchanged.
//      A-fragment read becomes a single swizzled b128 (was 2x f32x4 + cvt
//      per consuming wave per iter).
//  (2) Grid transposed to (N/128, M/128): the two blocks sharing an A-tile
//      are dispatch-adjacent -> partner A read hits L2 (FETCH was 314MB vs
//      268 ideal).
//  (3) pp16 layout: per-wave-contiguous 1KB stores (was 16B/lane at 128B
//      lane stride -> partial-line writes; WRITE_SIZE showed 202MB vs 67MB
//      ideal = 3x amplification). k_sp2 reads mirror the new layout.

constexpr int Bn   = 64;
constexpr int Hn   = 256;
constexpr int D2H  = 512;
constexpr int LPn  = 2048;
constexpr int LQn  = 64;

typedef __attribute__((ext_vector_type(8))) short bf16x8;
typedef __attribute__((ext_vector_type(4))) float f32x4;

typedef const __attribute__((address_space(1))) unsigned int* gup;
typedef __attribute__((address_space(3))) unsigned int* lup;
__device__ inline void async16(const void* g, void* l) {
  __builtin_amdgcn_global_load_lds((gup)g, (lup)l, 16, 0, 0);
}

__device__ inline float waveAllSum(float v) {
  #pragma unroll
  for (int o = 32; o > 0; o >>= 1) v += __shfl_xor(v, o, 64);
  return v;
}
__device__ inline float waveAllMax(float v) {
  #pragma unroll
  for (int o = 32; o > 0; o >>= 1) v = fmaxf(v, __shfl_xor(v, o, 64));
  return v;
}

__device__ inline short f2bf_rtne(float f) {
  union { float f; unsigned u; } v; v.f = f;
  unsigned r = v.u + 0x7FFF + ((v.u >> 16) & 1);
  return (short)(r >> 16);
}
__device__ inline unsigned pk2(float lo, float hi) {
  union { float f; unsigned u; } a, b; a.f = lo; b.f = hi;
  return __builtin_amdgcn_perm(b.u + 0x8000u, a.u + 0x8000u, 0x07060302u);
}
__device__ inline bf16x8 cvt8(f32x4 a0, f32x4 a1) {
  union { unsigned u[4]; bf16x8 v; } r;
  r.u[0] = pk2(a0[0], a0[1]);
  r.u[1] = pk2(a0[2], a0[3]);
  r.u[2] = pk2(a1[0], a1[1]);
  r.u[3] = pk2(a1[2], a1[3]);
  return r.v;
}

// -------- W -> plain row-major bf16 --------
__global__ __launch_bounds__(256) void k_wcvt(const float* __restrict__ WQu,
                                              const float* __restrict__ WPh,
                                              short* __restrict__ q16,
                                              short* __restrict__ p16) {
  int e = (blockIdx.x * 256 + threadIdx.x) * 4;
  const float* src; short* dst; int off;
  if (e < 131072) { src = WQu; dst = q16; off = e; }
  else            { src = WPh; dst = p16; off = e - 131072; }
  f32x4 f = *(const f32x4*)&src[off];
  short4 h;
  h.x = f2bf_rtne(f[0]); h.y = f2bf_rtne(f[1]);
  h.z = f2bf_rtne(f[2]); h.w = f2bf_rtne(f[3]);
  *(short4*)&dst[off] = h;
}

// -------- tiny: v2 = VQr @ WQv_W.T + WQv_b --------
__global__ __launch_bounds__(256) void k_v2(const float* __restrict__ VQr,
                                            const float* __restrict__ WQv_W,
                                            const float* __restrict__ WQv_b,
                                            float* __restrict__ v2) {
  __shared__ float s[256];
  int t = threadIdx.x;
  s[t] = VQr[t];
  __syncthreads();
  float acc = WQv_b[t];
  for (int k = 0; k < 256; ++k) acc += s[k] * WQv_W[t * 256 + k];
  v2[t] = acc;
}

// -------- fused MFMA GEMM + tanh-dot epilogue (bf16 LDS both operands) ----
// grid (2, M/128). Block: 128 rows x 128 cols, 4 waves (wave = 64x64).
__global__ __launch_bounds__(256, 4) void k_mfma(
    const float* __restrict__ A,     // [M][512] fp32
    const short* __restrict__ Wb,    // [256][512] bf16 row-major
    const float* __restrict__ bias,  // [256]
    const float* __restrict__ u,     // ustride=256: [64][256]; 0: [256]
    const float* __restrict__ vt,    // [64][256]
    short* __restrict__ pp,          // nullable: bf16 C store (wave-flat)
    float* __restrict__ sOut,        // [64][sstride], atomicAdd target
    int ustride, int sstride)
{
  __shared__ union {
    struct { short As[128 * 64]; short Bs[128 * 64]; } m;  // 16KB + 16KB
    float sred[256];
  } sm;
  const int t = threadIdx.x;
  const int w = t >> 6, l = t & 63, l15 = l & 15, quad = l >> 4;
  const int wm = w >> 1, wn = w & 1;
  const long bm = (long)blockIdx.y * 128;   // M tile
  const int n0 = blockIdx.x * 128;          // N half

  f32x4 acc[4][4];
  #pragma unroll
  for (int i = 0; i < 4; ++i)
    #pragma unroll
    for (int j = 0; j < 4; ++j)
      acc[i][j] = (f32x4)0.f;

  // B staging source (XOR-swizzled chunk within row, 8x 16B chunks/row)
  const short* gB = Wb + (size_t)(n0 + (t >> 3)) * 512 + (((t & 7) ^ ((t >> 3) & 7)) << 3);
  short* lB = sm.m.Bs + t * 8;

  for (int k0 = 0; k0 < 512; k0 += 64) {
    // B: async global->LDS (bf16 already), 32 rows per round
    #pragma unroll
    for (int it = 0; it < 4; ++it)
      async16(gB + it * 16384 + k0, lB + it * 2048);
    // A: fp32 global -> regs -> bf16 LDS (swizzled like B).
    // e = s*256+t: row = e>>3 (0..127), chunk c = e&7 (8 floats each).
    f32x4 a0[4], a1[4];
    #pragma unroll
    for (int s = 0; s < 4; ++s) {
      const int e = s * 256 + t, row = e >> 3, c = e & 7;
      const float* g = A + (bm + row) * 512 + k0 + (c << 3);
      a0[s] = *(const f32x4*)g;
      a1[s] = *(const f32x4*)(g + 4);
    }
    #pragma unroll
    for (int s = 0; s < 4; ++s) {
      const int e = s * 256 + t, row = e >> 3, c = e & 7;
      *(bf16x8*)&sm.m.As[row * 64 + ((c ^ (row & 7)) << 3)] = cvt8(a0[s], a1[s]);
    }
    __syncthreads();
    #pragma unroll
    for (int ks = 0; ks < 2; ++ks) {
      bf16x8 af[4], bfv[4];
      const int cc = ks * 4 + quad;         // 8-bf16 chunk index along K
      #pragma unroll
      for (int i = 0; i < 4; ++i) {
        const int R = wm * 64 + i * 16 + l15;       // R & 7 == l15 & 7
        af[i] = *(const bf16x8*)&sm.m.As[R * 64 + ((cc ^ (l15 & 7)) << 3)];
      }
      #pragma unroll
      for (int j = 0; j < 4; ++j) {
        const int R = wn * 64 + j * 16 + l15;       // R & 7 == l15 & 7
        bfv[j] = *(const bf16x8*)&sm.m.Bs[R * 64 + ((cc ^ (l15 & 7)) << 3)];
      }
      #pragma unroll
      for (int i = 0; i < 4; ++i)
        #pragma unroll
        for (int j = 0; j < 4; ++j)
          acc[i][j] = __builtin_amdgcn_mfma_f32_16x16x32_bf16(af[i], bfv[j], acc[i][j], 0, 0, 0);
    }
    __syncthreads();
  }

  // epilogue: bias, optional bf16 C store (wave-contiguous layout), tanh-dot
  // pp group = blockIdx.y*2 + blockIdx.x; within: w*4096 + (i*2+s)*512 + l*8
  short* ppt = pp ? pp + (((size_t)blockIdx.y * 2 + blockIdx.x) * 16384 + (size_t)w * 4096 + l * 8)
                  : nullptr;
  float srow[4][4];
  #pragma unroll
  for (int i = 0; i < 4; ++i) {
    #pragma unroll
    for (int r = 0; r < 4; ++r) srow[i][r] = 0.f;
    unsigned pk[8];
    const int bb = i * 16 + quad * 4;
    #pragma unroll
    for (int j = 0; j < 4; ++j) {
      const int n = n0 + wn * 64 + j * 16 + l15;
      const float bn = bias[n];
      float v0 = acc[i][j][0] + bn, v1 = acc[i][j][1] + bn;
      float v2 = acc[i][j][2] + bn, v3 = acc[i][j][3] + bn;
      if (ppt) { pk[j * 2] = pk2(v0, v1); pk[j * 2 + 1] = pk2(v2, v3); }
      srow[i][0] += tanhf(v0 + u[ustride * (bb + 0) + n]) * vt[(bb + 0) * 256 + n];
      srow[i][1] += tanhf(v1 + u[ustride * (bb + 1) + n]) * vt[(bb + 1) * 256 + n];
      srow[i][2] += tanhf(v2 + u[ustride * (bb + 2) + n]) * vt[(bb + 2) * 256 + n];
      srow[i][3] += tanhf(v3 + u[ustride * (bb + 3) + n]) * vt[(bb + 3) * 256 + n];
    }
    if (ppt) {
      uint4 s0 = {pk[0], pk[1], pk[2], pk[3]};
      uint4 s1 = {pk[4], pk[5], pk[6], pk[7]};
      *(uint4*)&ppt[i * 1024]       = s0;   // per-instr: 64 lanes x 16B contiguous
      *(uint4*)&ppt[i * 1024 + 512] = s1;
    }
  }
  #pragma unroll
  for (int off = 1; off < 16; off <<= 1)
    #pragma unroll
    for (int i = 0; i < 4; ++i)
      #pragma unroll
      for (int r = 0; r < 4; ++r)
        srow[i][r] += __shfl_xor(srow[i][r], off, 64);
  if (l15 == 0)
    #pragma unroll
    for (int i = 0; i < 4; ++i)
      #pragma unroll
      for (int r = 0; r < 4; ++r)
        sm.sred[wn * 128 + wm * 64 + i * 16 + quad * 4 + r] = srow[i][r];
  __syncthreads();
  if (t < 128) {
    float s = sm.sred[t] + sm.sred[128 + t];
    int b = t & 63;
    int pg = blockIdx.y * 2 + (t >> 6);
    atomicAdd(&sOut[(size_t)b * sstride + pg], s);
  }
}

// -------- pointer step 2: epilogue replay from bf16 passP --------
__global__ __launch_bounds__(256) void k_sp2(const short* __restrict__ pp,
                                             const float* __restrict__ u2,
                                             const float* __restrict__ vt,
                                             float* __restrict__ sP) {
  __shared__ float sred[256];
  const int g = blockIdx.x, t = threadIdx.x;
  const int w = t >> 6, l = t & 63, l15 = l & 15, quad = l >> 4;
  const int wm = w >> 1, wn = w & 1;
  const int n0 = (g & 1) * 128;
  const short* src = pp + (size_t)g * 16384 + (size_t)w * 4096 + l * 8;
  float srow[4][4];
  #pragma unroll
  for (int i = 0; i < 4; ++i) {
    uint4 q0 = *(const uint4*)&src[i * 1024];
    uint4 q1 = *(const uint4*)&src[i * 1024 + 512];
    unsigned pk[8] = {q0.x, q0.y, q0.z, q0.w, q1.x, q1.y, q1.z, q1.w};
    #pragma unroll
    for (int r = 0; r < 4; ++r) srow[i][r] = 0.f;
    const int bb = i * 16 + quad * 4;
    #pragma unroll
    for (int j = 0; j < 4; ++j) {
      const int n = n0 + wn * 64 + j * 16 + l15;
      #pragma unroll
      for (int r = 0; r < 4; ++r) {
        unsigned word = pk[j * 2 + (r >> 1)];
        unsigned bits = (r & 1) ? (word & 0xFFFF0000u) : (word << 16);
        float val = __uint_as_float(bits);
        srow[i][r] += tanhf(val + u2[(bb + r) * 256 + n]) * vt[(bb + r) * 256 + n];
      }
    }
  }
  #pragma unroll
  for (int off = 1; off < 16; off <<= 1)
    #pragma unroll
    for (int i = 0; i < 4; ++i)
      #pragma unroll
      for (int r = 0; r < 4; ++r)
        srow[i][r] += __shfl_xor(srow[i][r], off, 64);
  if (l15 == 0)
    #pragma unroll
    for (int i = 0; i < 4; ++i)
      #pragma unroll
      for (int r = 0; r < 4; ++r)
        sred[wn * 128 + wm * 64 + i * 16 + quad * 4 + r] = srow[i][r];
  __syncthreads();
  if (t < 128) {
    float s = sred[t] + sred[128 + t];
    int b = t & 63;
    int pg = (g >> 1) * 2 + (t >> 6);
    atomicAdd(&sP[(size_t)b * LPn + pg], s);
  }
}

// -------- softmax(sQ) -> rQ -> u1, one block per b --------
__global__ __launch_bounds__(256) void k_rq_u1(const float* __restrict__ sQ,
                                               const float* __restrict__ quesEnc,
                                               const float* __restrict__ Wah,
                                               const float* __restrict__ Wah_b,
                                               float* __restrict__ rQ,
                                               float* __restrict__ u1) {
  int b = blockIdx.x, tid = threadIdx.x;
  __shared__ float s_a[LQn];
  __shared__ float s_r[D2H];
  if (tid < 64) {
    float s = sQ[b * LQn + tid];
    float m = waveAllMax(s);
    float e = expf(s - m);
    float sum = waveAllSum(e);
    s_a[tid] = e / sum;
  }
  __syncthreads();
  #pragma unroll
  for (int rep = 0; rep < 2; ++rep) {
    int d = tid + rep * 256;
    float acc = 0.f;
    for (int q = 0; q < LQn; ++q)
      acc += s_a[q] * quesEnc[(size_t)(q * Bn + b) * D2H + d];
    s_r[d] = acc;
    rQ[b * D2H + d] = acc;
  }
  __syncthreads();
  float accu = Wah_b[tid];
  const float* wr = Wah + (size_t)tid * 512;
  for (int k4 = 0; k4 < 128; ++k4) {
    f32x4 wv = *(const f32x4*)&wr[k4 * 4];
    f32x4 rv = *(const f32x4*)&s_r[k4 * 4];
    accu += wv[0] * rv[0] + wv[1] * rv[1] + wv[2] * rv[2] + wv[3] * rv[3];
  }
  u1[b * Hn + tid] = accu;
}

// -------- softmax over 2048, one block per b --------
__global__ __launch_bounds__(256) void k_softmax(const float* __restrict__ sP,
                                                 float* __restrict__ out) {
  int b = blockIdx.x, tid = threadIdx.x;
  int lane = tid & 63, wid = tid >> 6;
  __shared__ float red[4];
  float v[8];
  float m = -1e30f;
  #pragma unroll
  for (int i = 0; i < 8; ++i) {
    v[i] = sP[b * LPn + i * 256 + tid];
    m = fmaxf(m, v[i]);
  }
  m = waveAllMax(m);
  if (lane == 0) red[wid] = m;
  __syncthreads();
  m = fmaxf(fmaxf(red[0], red[1]), fmaxf(red[2], red[3]));
  float s = 0.f;
  #pragma unroll
  for (int i = 0; i < 8; ++i) { v[i] = expf(v[i] - m); s += v[i]; }
  s = waveAllSum(s);
  __syncthreads();
  if (lane == 0) red[wid] = s;
  __syncthreads();
  s = red[0] + red[1] + red[2] + red[3];
  float inv = 1.0f / s;
  #pragma unroll
  for (int i = 0; i < 8; ++i) out[b * LPn + i * 256 + tid] = v[i] * inv;
}

// -------- ct[b][d] = sum_p aP[b][p]*passEnc[p,b,d], grid (64,32) --------
__global__ __launch_bounds__(256) void k_ct(const float* __restrict__ aP,
                                            const float* __restrict__ passEnc,
                                            float* __restrict__ ct) {
  int b = blockIdx.x, pc = blockIdx.y, tid = threadIdx.x;
  int dg = tid & 127;
  int pg = tid >> 7;
  f32x4 acc = (f32x4)0.f;
  #pragma unroll
  for (int pp = 0; pp < 32; ++pp) {
    int p = pc * 64 + pg * 32 + pp;
    float a = aP[b * LPn + p];
    acc += a * *(const f32x4*)&passEnc[((size_t)p * Bn + b) * D2H + dg * 4];
  }
  __shared__ f32x4 sacc[256];
  sacc[tid] = acc;
  __syncthreads();
  if (pg == 0) {
    acc += sacc[tid + 128];
    float* dst = &ct[b * D2H + dg * 4];
    atomicAdd(dst + 0, acc[0]);
    atomicAdd(dst + 1, acc[1]);
    atomicAdd(dst + 2, acc[2]);
    atomicAdd(dst + 3, acc[3]);
  }
}

// -------- GRU mat-vecs, weight-stationary: grid 192 --------
__global__ __launch_bounds__(256) void k_gih(const float* __restrict__ rQ,
                                             const float* __restrict__ ct,
                                             const float* __restrict__ wih,
                                             const float* __restrict__ whh,
                                             const float* __restrict__ bih,
                                             const float* __restrict__ bhh,
                                             float* __restrict__ gi,
                                             float* __restrict__ gh) {
  __shared__ float sw[16 * 512];
  int blk = blockIdx.x;
  bool isH = blk >= 96;
  const float* W = isH ? whh : wih;
  const float* X = isH ? ct : rQ;
  const float* bias = isH ? bhh : bih;
  float* G = isH ? gh : gi;
  int r0 = (isH ? blk - 96 : blk) * 16;
  int t = threadIdx.x;
  #pragma unroll
  for (int it = 0; it < 8; ++it) {
    int f4 = it * 256 + t;
    *(f32x4*)&sw[f4 * 4] = *(const f32x4*)&W[(size_t)r0 * 512 + f4 * 4];
  }
  __syncthreads();
  int b = t & 63;
  int rbase = (t >> 6) * 4;
  const float* x = X + b * 512;
  float acc[4];
  #pragma unroll
  for (int oo = 0; oo < 4; ++oo) acc[oo] = bias[r0 + rbase + oo];
  for (int k4 = 0; k4 < 128; ++k4) {
    f32x4 xv = *(const f32x4*)&x[k4 * 4];
    #pragma unroll
    for (int oo = 0; oo < 4; ++oo) {
      f32x4 wv = *(const f32x4*)&sw[(rbase + oo) * 512 + k4 * 4];
      acc[oo] += wv[0] * xv[0] + wv[1] * xv[1] + wv[2] * xv[2] + wv[3] * xv[3];
    }
  }
  #pragma unroll
  for (int oo = 0; oo < 4; ++oo)
    G[b * 1536 + r0 + rbase + oo] = acc[oo];
}

// -------- GRU gates -> rQ2 --------
__global__ __launch_bounds__(256) void k_gates(const float* __restrict__ gi,
                                               const float* __restrict__ gh,
                                               const float* __restrict__ ct,
                                               float* __restrict__ rQ2) {
  int idx = blockIdx.x * 256 + threadIdx.x;
  int b = idx >> 9;
  int j = idx & 511;
  const float* gib = gi + b * 1536;
  const float* ghb = gh + b * 1536;
  float r = 1.f / (1.f + expf(-(gib[j] + ghb[j])));
  float z = 1.f / (1.f + expf(-(gib[512 + j] + ghb[512 + j])));
  float n = tanhf(gib[1024 + j] + r * ghb[1024 + j]);
  rQ2[b * D2H + j] = (1.f - z) * n + z * ct[b * D2H + j];
}

// -------- u2[m][n] = Wah[n] . rQ2[m] + Wah_b[n], grid 64 --------
__global__ __launch_bounds__(256) void k_u2(const float* __restrict__ rQ2,
                                            const float* __restrict__ Wah,
                                            const float* __restrict__ Wah_b,
                                            float* __restrict__ u2) {
  int m = blockIdx.x, n = threadIdx.x;
  __shared__ float s_r[D2H];
  s_r[n]       = rQ2[m * D2H + n];
  s_r[n + 256] = rQ2[m * D2H + n + 256];
  __syncthreads();
  float acc = Wah_b[n];
  const float* wr = Wah + (size_t)n * 512;
  for (int k4 = 0; k4 < 128; ++k4) {
    f32x4 wv = *(const f32x4*)&wr[k4 * 4];
    f32x4 rv = *(const f32x4*)&s_r[k4 * 4];
    acc += wv[0] * rv[0] + wv[1] * rv[1] + wv[2] * rv[2] + wv[3] * rv[3];
  }
  u2[m * Hn + n] = acc;
}

extern "C" void kernel_launch(void* const* d_in, const int* in_sizes, int n_in,
                              void* d_out, int out_size, void* d_ws, size_t ws_size,
                              hipStream_t stream) {
  const float* passEnc  = (const float*)d_in[0];
  const float* quesEnc  = (const float*)d_in[1];
  const float* WQu_W    = (const float*)d_in[2];
  const float* WQu_b    = (const float*)d_in[3];
  const float* WQv_W    = (const float*)d_in[4];
  const float* WQv_b    = (const float*)d_in[5];
  const float* WPh_W    = (const float*)d_in[6];
  const float* WPh_b    = (const float*)d_in[7];
  const float* Wah_W    = (const float*)d_in[8];
  const float* Wah_b    = (const float*)d_in[9];
  const float* Vt1      = (const float*)d_in[10];
  const float* Vt2      = (const float*)d_in[11];
  const float* VQr      = (const float*)d_in[12];
  const float* gru_wih  = (const float*)d_in[13];
  const float* gru_whh  = (const float*)d_in[14];
  const float* gru_bih  = (const float*)d_in[15];
  const float* gru_bhh  = (const float*)d_in[16];
  float* out = (float*)d_out;

  float* ws = (float*)d_ws;
  float* v2    = ws;                    // 256
  float* rQ    = v2 + 256;              // 32768
  float* u1    = rQ + 32768;            // 16384
  float* u2    = u1 + 16384;            // 16384
  float* sP    = u2 + 16384;            // 131072
  float* ct    = sP + 131072;           // 32768
  float* gi    = ct + 32768;            // 98304
  float* gh    = gi + 98304;            // 98304
  float* rQ2   = gh + 98304;            // 32768
  float* sQ    = rQ2 + 32768;           // 4096
  short* wqu16 = (short*)(sQ + 4096);   // 131072 shorts
  short* wph16 = wqu16 + 131072;        // 131072 shorts
  short* pp16  = wph16 + 131072;        // 33554432 shorts (67MB)

  hipMemsetAsync(sQ, 0, Bn * LQn * sizeof(float), stream);
  hipMemsetAsync(sP, 0, Bn * LPn * sizeof(float), stream);
  hipMemsetAsync(ct, 0, Bn * D2H * sizeof(float), stream);

  k_wcvt<<<256, 256, 0, stream>>>(WQu_W, WPh_W, wqu16, wph16);
  k_v2<<<1, 256, 0, stream>>>(VQr, WQv_W, WQv_b, v2);

  // question path: GEMM + sQ epilogue (no pp store). grid (N-halves, M-tiles)
  k_mfma<<<dim3(2, LQn * Bn / 128), 256, 0, stream>>>(
      quesEnc, wqu16, WQu_b, v2, Vt1, nullptr, sQ, 0, LQn);
  k_rq_u1<<<Bn, 256, 0, stream>>>(sQ, quesEnc, Wah_W, Wah_b, rQ, u1);

  // pointer step 1: pass GEMM + sP1 epilogue + bf16 passP store
  k_mfma<<<dim3(2, LPn * Bn / 128), 256, 0, stream>>>(
      passEnc, wph16, WPh_b, u1, Vt2, pp16, sP, Hn, LPn);
  k_softmax<<<Bn, 256, 0, stream>>>(sP, out);  // aP1

  k_ct<<<dim3(Bn, 32), 256, 0, stream>>>(out, passEnc, ct);

  k_gih<<<192, 256, 0, stream>>>(rQ, ct, gru_wih, gru_whh, gru_bih, gru_bhh, gi, gh);
  k_gates<<<Bn * D2H / 256, 256, 0, stream>>>(gi, gh, ct, rQ2);
  k_u2<<<Bn, 256, 0, stream>>>(rQ2, Wah_W, Wah_b, u2);

  // pointer step 2: epilogue replay from bf16 passP
  hipMemsetAsync(sP, 0, Bn * LPn * sizeof(float), stream);
  k_sp2<<<LPn * Bn / 64, 256, 0, stream>>>(pp16, u2, Vt2, sP);
  k_softmax<<<Bn, 256, 0, stream>>>(sP, out + Bn * LPn);  // aP2
}

// Round 3
// 902.269 us; speedup vs baseline: 1.0221x; 1.0221x over previous
//
#include <hip/hip_runtime.h>
#include <math.h>

// AnswerPointerNetwork: H=256, B=64, LP=2048, LQ=64, fp32 in/out.
// R8: post-mortem of R7 showed __launch_bounds__(256,4) + 32 reg-staged
// A-floats forced VGPR=64 -> scratch spill (FETCH +130MB, WRITE +86MB,
// dur 260->310). Fix by removing the staging entirely:
//  (1) k_acvt: pre-convert passEnc+quesEnc fp32->bf16 (one streaming pass,
//      ~70us). k_mfma A becomes bf16 like B -> pure global_load_lds staging,
//      zero staging VGPRs, zero in-loop cvt, A GEMM traffic halves (134MB).
//  (2) A and B use the identical XOR-swizzled async16 pattern; fragment
//      reads are 2-way-aliased b128 (free per m136).
//  (3) Partner blocks (same M-tile, two N-halves) placed 8 apart in linear
//      blockIdx -> same XCD under round-robin dispatch -> A-tile partner
//      read hits that XCD's L2 (tile 128KB << 4MB).
//  (4) keep (256,4): without staging regs, peak live ~48 VGPR + 64 AGPR
//      fits the 128 budget without spill.

constexpr int Bn   = 64;
constexpr int Hn   = 256;
constexpr int D2H  = 512;
constexpr int LPn  = 2048;
constexpr int LQn  = 64;

typedef __attribute__((ext_vector_type(8))) short bf16x8;
typedef __attribute__((ext_vector_type(4))) float f32x4;

typedef const __attribute__((address_space(1))) unsigned int* gup;
typedef __attribute__((address_space(3))) unsigned int* lup;
__device__ inline void async16(const void* g, void* l) {
  __builtin_amdgcn_global_load_lds((gup)g, (lup)l, 16, 0, 0);
}

__device__ inline float waveAllSum(float v) {
  #pragma unroll
  for (int o = 32; o > 0; o >>= 1) v += __shfl_xor(v, o, 64);
  return v;
}
__device__ inline float waveAllMax(float v) {
  #pragma unroll
  for (int o = 32; o > 0; o >>= 1) v = fmaxf(v, __shfl_xor(v, o, 64));
  return v;
}

__device__ inline short f2bf_rtne(float f) {
  union { float f; unsigned u; } v; v.f = f;
  unsigned r = v.u + 0x7FFF + ((v.u >> 16) & 1);
  return (short)(r >> 16);
}
__device__ inline unsigned pk2(float lo, float hi) {
  union { float f; unsigned u; } a, b; a.f = lo; b.f = hi;
  return __builtin_amdgcn_perm(b.u + 0x8000u, a.u + 0x8000u, 0x07060302u);
}
__device__ inline bf16x8 cvt8(f32x4 a0, f32x4 a1) {
  union { unsigned u[4]; bf16x8 v; } r;
  r.u[0] = pk2(a0[0], a0[1]);
  r.u[1] = pk2(a0[2], a0[3]);
  r.u[2] = pk2(a1[0], a1[1]);
  r.u[3] = pk2(a1[2], a1[3]);
  return r.v;
}

// -------- W -> plain row-major bf16 --------
__global__ __launch_bounds__(256) void k_wcvt(const float* __restrict__ WQu,
                                              const float* __restrict__ WPh,
                                              short* __restrict__ q16,
                                              short* __restrict__ p16) {
  int e = (blockIdx.x * 256 + threadIdx.x) * 4;
  const float* src; short* dst; int off;
  if (e < 131072) { src = WQu; dst = q16; off = e; }
  else            { src = WPh; dst = p16; off = e - 131072; }
  f32x4 f = *(const f32x4*)&src[off];
  short4 h;
  h.x = f2bf_rtne(f[0]); h.y = f2bf_rtne(f[1]);
  h.z = f2bf_rtne(f[2]); h.w = f2bf_rtne(f[3]);
  *(short4*)&dst[off] = h;
}

// -------- passEnc + quesEnc fp32 -> bf16 (streaming, BW-bound) --------
__global__ __launch_bounds__(256) void k_acvt(const float* __restrict__ pe,
                                              const float* __restrict__ qe,
                                              short* __restrict__ pe16,
                                              short* __restrict__ qe16) {
  const long NPG = 8388608;   // passEnc f32x8 groups (2048*64*512/8)
  const long NG  = 8650752;   // + quesEnc groups (64*64*512/8)
  for (long g = (long)blockIdx.x * 256 + threadIdx.x; g < NG;
       g += (long)gridDim.x * 256) {
    const float* src; short* dst; long off;
    if (g < NPG) { src = pe; dst = pe16; off = g << 3; }
    else         { src = qe; dst = qe16; off = (g - NPG) << 3; }
    f32x4 a = *(const f32x4*)&src[off];
    f32x4 b = *(const f32x4*)&src[off + 4];
    *(bf16x8*)&dst[off] = cvt8(a, b);
  }
}

// -------- tiny: v2 = VQr @ WQv_W.T + WQv_b --------
__global__ __launch_bounds__(256) void k_v2(const float* __restrict__ VQr,
                                            const float* __restrict__ WQv_W,
                                            const float* __restrict__ WQv_b,
                                            float* __restrict__ v2) {
  __shared__ float s[256];
  int t = threadIdx.x;
  s[t] = VQr[t];
  __syncthreads();
  float acc = WQv_b[t];
  for (int k = 0; k < 256; ++k) acc += s[k] * WQv_W[t * 256 + k];
  v2[t] = acc;
}

// -------- fused MFMA GEMM + tanh-dot epilogue (all-bf16 async staging) ----
// 1-D grid, 2 blocks per M-tile (N halves). Partner pair 8 apart in linear
// id (same XCD). Block: 128 rows x 128 cols, 4 waves (wave = 64x64).
__global__ __launch_bounds__(256, 4) void k_mfma(
    const short* __restrict__ Ab,    // [M][512] bf16 row-major
    const short* __restrict__ Wb,    // [256][512] bf16 row-major
    const float* __restrict__ bias,  // [256]
    const float* __restrict__ u,     // ustride=256: [64][256]; 0: [256]
    const float* __restrict__ vt,    // [64][256]
    short* __restrict__ pp,          // nullable: bf16 C store (wave-flat)
    float* __restrict__ sOut,        // [64][sstride], atomicAdd target
    int ustride, int sstride)
{
  __shared__ union {
    struct { short As[128 * 64]; short Bs[128 * 64]; } m;  // 16KB + 16KB
    float sred[256];
  } sm;
  const int t = threadIdx.x;
  const int w = t >> 6, l = t & 63, l15 = l & 15, quad = l >> 4;
  const int wm = w >> 1, wn = w & 1;
  // pair-swizzle: lin = grp*16 + half*8 + pairLocal
  const int lin   = blockIdx.x;
  const int grp   = lin >> 4;
  const int half  = (lin & 15) >> 3;
  const int mtile = grp * 8 + (lin & 7);
  const long bm = (long)mtile * 128;
  const int n0 = half * 128;

  f32x4 acc[4][4];
  #pragma unroll
  for (int i = 0; i < 4; ++i)
    #pragma unroll
    for (int j = 0; j < 4; ++j)
      acc[i][j] = (f32x4)0.f;

  // staging sources (XOR-swizzled 16B chunk within row; 8 chunks per 64-K)
  const short* gA = Ab + (size_t)(bm + (t >> 3)) * 512 + (((t & 7) ^ ((t >> 3) & 7)) << 3);
  const short* gB = Wb + (size_t)(n0 + (t >> 3)) * 512 + (((t & 7) ^ ((t >> 3) & 7)) << 3);
  short* lA = sm.m.As + t * 8;
  short* lB = sm.m.Bs + t * 8;

  for (int k0 = 0; k0 < 512; k0 += 64) {
    #pragma unroll
    for (int it = 0; it < 4; ++it)
      async16(gA + it * 16384 + k0, lA + it * 2048);   // 32 rows / round
    #pragma unroll
    for (int it = 0; it < 4; ++it)
      async16(gB + it * 16384 + k0, lB + it * 2048);
    __syncthreads();
    #pragma unroll
    for (int ks = 0; ks < 2; ++ks) {
      bf16x8 af[4], bfv[4];
      const int cc = ks * 4 + quad;         // 8-bf16 chunk index along K
      #pragma unroll
      for (int i = 0; i < 4; ++i) {
        const int R = wm * 64 + i * 16 + l15;       // R & 7 == l15 & 7
        af[i] = *(const bf16x8*)&sm.m.As[R * 64 + ((cc ^ (l15 & 7)) << 3)];
      }
      #pragma unroll
      for (int j = 0; j < 4; ++j) {
        const int R = wn * 64 + j * 16 + l15;
        bfv[j] = *(const bf16x8*)&sm.m.Bs[R * 64 + ((cc ^ (l15 & 7)) << 3)];
      }
      #pragma unroll
      for (int i = 0; i < 4; ++i)
        #pragma unroll
        for (int j = 0; j < 4; ++j)
          acc[i][j] = __builtin_amdgcn_mfma_f32_16x16x32_bf16(af[i], bfv[j], acc[i][j], 0, 0, 0);
    }
    __syncthreads();
  }

  // epilogue: bias, optional bf16 C store (wave-contiguous layout), tanh-dot
  // pp group = mtile*2 + half; within: w*4096 + (i*2+s)*512 + l*8
  short* ppt = pp ? pp + (((size_t)mtile * 2 + half) * 16384 + (size_t)w * 4096 + l * 8)
                  : nullptr;
  float srow[4][4];
  #pragma unroll
  for (int i = 0; i < 4; ++i) {
    #pragma unroll
    for (int r = 0; r < 4; ++r) srow[i][r] = 0.f;
    unsigned pk[8];
    const int bb = i * 16 + quad * 4;
    #pragma unroll
    for (int j = 0; j < 4; ++j) {
      const int n = n0 + wn * 64 + j * 16 + l15;
      const float bn = bias[n];
      float v0 = acc[i][j][0] + bn, v1 = acc[i][j][1] + bn;
      float v2 = acc[i][j][2] + bn, v3 = acc[i][j][3] + bn;
      if (ppt) { pk[j * 2] = pk2(v0, v1); pk[j * 2 + 1] = pk2(v2, v3); }
      srow[i][0] += tanhf(v0 + u[ustride * (bb + 0) + n]) * vt[(bb + 0) * 256 + n];
      srow[i][1] += tanhf(v1 + u[ustride * (bb + 1) + n]) * vt[(bb + 1) * 256 + n];
      srow[i][2] += tanhf(v2 + u[ustride * (bb + 2) + n]) * vt[(bb + 2) * 256 + n];
      srow[i][3] += tanhf(v3 + u[ustride * (bb + 3) + n]) * vt[(bb + 3) * 256 + n];
    }
    if (ppt) {
      uint4 s0 = {pk[0], pk[1], pk[2], pk[3]};
      uint4 s1 = {pk[4], pk[5], pk[6], pk[7]};
      *(uint4*)&ppt[i * 1024]       = s0;   // per-instr: 64 lanes x 16B contiguous
      *(uint4*)&ppt[i * 1024 + 512] = s1;
    }
  }
  #pragma unroll
  for (int off = 1; off < 16; off <<= 1)
    #pragma unroll
    for (int i = 0; i < 4; ++i)
      #pragma unroll
      for (int r = 0; r < 4; ++r)
        srow[i][r] += __shfl_xor(srow[i][r], off, 64);
  if (l15 == 0)
    #pragma unroll
    for (int i = 0; i < 4; ++i)
      #pragma unroll
      for (int r = 0; r < 4; ++r)
        sm.sred[wn * 128 + wm * 64 + i * 16 + quad * 4 + r] = srow[i][r];
  __syncthreads();
  if (t < 128) {
    float s = sm.sred[t] + sm.sred[128 + t];
    int b = t & 63;
    int pg = mtile * 2 + (t >> 6);
    atomicAdd(&sOut[(size_t)b * sstride + pg], s);
  }
}

// -------- pointer step 2: epilogue replay from bf16 passP --------
__global__ __launch_bounds__(256) void k_sp2(const short* __restrict__ pp,
                                             const float* __restrict__ u2,
                                             const float* __restrict__ vt,
                                             float* __restrict__ sP) {
  __shared__ float sred[256];
  const int g = blockIdx.x, t = threadIdx.x;
  const int w = t >> 6, l = t & 63, l15 = l & 15, quad = l >> 4;
  const int wm = w >> 1, wn = w & 1;
  const int n0 = (g & 1) * 128;
  const short* src = pp + (size_t)g * 16384 + (size_t)w * 4096 + l * 8;
  float srow[4][4];
  #pragma unroll
  for (int i = 0; i < 4; ++i) {
    uint4 q0 = *(const uint4*)&src[i * 1024];
    uint4 q1 = *(const uint4*)&src[i * 1024 + 512];
    unsigned pk[8] = {q0.x, q0.y, q0.z, q0.w, q1.x, q1.y, q1.z, q1.w};
    #pragma unroll
    for (int r = 0; r < 4; ++r) srow[i][r] = 0.f;
    const int bb = i * 16 + quad * 4;
    #pragma unroll
    for (int j = 0; j < 4; ++j) {
      const int n = n0 + wn * 64 + j * 16 + l15;
      #pragma unroll
      for (int r = 0; r < 4; ++r) {
        unsigned word = pk[j * 2 + (r >> 1)];
        unsigned bits = (r & 1) ? (word & 0xFFFF0000u) : (word << 16);
        float val = __uint_as_float(bits);
        srow[i][r] += tanhf(val + u2[(bb + r) * 256 + n]) * vt[(bb + r) * 256 + n];
      }
    }
  }
  #pragma unroll
  for (int off = 1; off < 16; off <<= 1)
    #pragma unroll
    for (int i = 0; i < 4; ++i)
      #pragma unroll
      for (int r = 0; r < 4; ++r)
        srow[i][r] += __shfl_xor(srow[i][r], off, 64);
  if (l15 == 0)
    #pragma unroll
    for (int i = 0; i < 4; ++i)
      #pragma unroll
      for (int r = 0; r < 4; ++r)
        sred[wn * 128 + wm * 64 + i * 16 + quad * 4 + r] = srow[i][r];
  __syncthreads();
  if (t < 128) {
    float s = sred[t] + sred[128 + t];
    int b = t & 63;
    int pg = (g >> 1) * 2 + (t >> 6);
    atomicAdd(&sP[(size_t)b * LPn + pg], s);
  }
}

// -------- softmax(sQ) -> rQ -> u1, one block per b --------
__global__ __launch_bounds__(256) void k_rq_u1(const float* __restrict__ sQ,
                                               const float* __restrict__ quesEnc,
                                               const float* __restrict__ Wah,
                                               const float* __restrict__ Wah_b,
                                               float* __restrict__ rQ,
                                               float* __restrict__ u1) {
  int b = blockIdx.x, tid = threadIdx.x;
  __shared__ float s_a[LQn];
  __shared__ float s_r[D2H];
  if (tid < 64) {
    float s = sQ[b * LQn + tid];
    float m = waveAllMax(s);
    float e = expf(s - m);
    float sum = waveAllSum(e);
    s_a[tid] = e / sum;
  }
  __syncthreads();
  #pragma unroll
  for (int rep = 0; rep < 2; ++rep) {
    int d = tid + rep * 256;
    float acc = 0.f;
    for (int q = 0; q < LQn; ++q)
      acc += s_a[q] * quesEnc[(size_t)(q * Bn + b) * D2H + d];
    s_r[d] = acc;
    rQ[b * D2H + d] = acc;
  }
  __syncthreads();
  float accu = Wah_b[tid];
  const float* wr = Wah + (size_t)tid * 512;
  for (int k4 = 0; k4 < 128; ++k4) {
    f32x4 wv = *(const f32x4*)&wr[k4 * 4];
    f32x4 rv = *(const f32x4*)&s_r[k4 * 4];
    accu += wv[0] * rv[0] + wv[1] * rv[1] + wv[2] * rv[2] + wv[3] * rv[3];
  }
  u1[b * Hn + tid] = accu;
}

// -------- softmax over 2048, one block per b --------
__global__ __launch_bounds__(256) void k_softmax(const float* __restrict__ sP,
                                                 float* __restrict__ out) {
  int b = blockIdx.x, tid = threadIdx.x;
  int lane = tid & 63, wid = tid >> 6;
  __shared__ float red[4];
  float v[8];
  float m = -1e30f;
  #pragma unroll
  for (int i = 0; i < 8; ++i) {
    v[i] = sP[b * LPn + i * 256 + tid];
    m = fmaxf(m, v[i]);
  }
  m = waveAllMax(m);
  if (lane == 0) red[wid] = m;
  __syncthreads();
  m = fmaxf(fmaxf(red[0], red[1]), fmaxf(red[2], red[3]));
  float s = 0.f;
  #pragma unroll
  for (int i = 0; i < 8; ++i) { v[i] = expf(v[i] - m); s += v[i]; }
  s = waveAllSum(s);
  __syncthreads();
  if (lane == 0) red[wid] = s;
  __syncthreads();
  s = red[0] + red[1] + red[2] + red[3];
  float inv = 1.0f / s;
  #pragma unroll
  for (int i = 0; i < 8; ++i) out[b * LPn + i * 256 + tid] = v[i] * inv;
}

// -------- ct[b][d] = sum_p aP[b][p]*passEnc[p,b,d], grid (64,32) --------
__global__ __launch_bounds__(256) void k_ct(const float* __restrict__ aP,
                                            const float* __restrict__ passEnc,
                                            float* __restrict__ ct) {
  int b = blockIdx.x, pc = blockIdx.y, tid = threadIdx.x;
  int dg = tid & 127;
  int pg = tid >> 7;
  f32x4 acc = (f32x4)0.f;
  #pragma unroll
  for (int pp = 0; pp < 32; ++pp) {
    int p = pc * 64 + pg * 32 + pp;
    float a = aP[b * LPn + p];
    acc += a * *(const f32x4*)&passEnc[((size_t)p * Bn + b) * D2H + dg * 4];
  }
  __shared__ f32x4 sacc[256];
  sacc[tid] = acc;
  __syncthreads();
  if (pg == 0) {
    acc += sacc[tid + 128];
    float* dst = &ct[b * D2H + dg * 4];
    atomicAdd(dst + 0, acc[0]);
    atomicAdd(dst + 1, acc[1]);
    atomicAdd(dst + 2, acc[2]);
    atomicAdd(dst + 3, acc[3]);
  }
}

// -------- GRU mat-vecs, weight-stationary: grid 192 --------
__global__ __launch_bounds__(256) void k_gih(const float* __restrict__ rQ,
                                             const float* __restrict__ ct,
                                             const float* __restrict__ wih,
                                             const float* __restrict__ whh,
                                             const float* __restrict__ bih,
                                             const float* __restrict__ bhh,
                                             float* __restrict__ gi,
                                             float* __restrict__ gh) {
  __shared__ float sw[16 * 512];
  int blk = blockIdx.x;
  bool isH = blk >= 96;
  const float* W = isH ? whh : wih;
  const float* X = isH ? ct : rQ;
  const float* bias = isH ? bhh : bih;
  float* G = isH ? gh : gi;
  int r0 = (isH ? blk - 96 : blk) * 16;
  int t = threadIdx.x;
  #pragma unroll
  for (int it = 0; it < 8; ++it) {
    int f4 = it * 256 + t;
    *(f32x4*)&sw[f4 * 4] = *(const f32x4*)&W[(size_t)r0 * 512 + f4 * 4];
  }
  __syncthreads();
  int b = t & 63;
  int rbase = (t >> 6) * 4;
  const float* x = X + b * 512;
  float acc[4];
  #pragma unroll
  for (int oo = 0; oo < 4; ++oo) acc[oo] = bias[r0 + rbase + oo];
  for (int k4 = 0; k4 < 128; ++k4) {
    f32x4 xv = *(const f32x4*)&x[k4 * 4];
    #pragma unroll
    for (int oo = 0; oo < 4; ++oo) {
      f32x4 wv = *(const f32x4*)&sw[(rbase + oo) * 512 + k4 * 4];
      acc[oo] += wv[0] * xv[0] + wv[1] * xv[1] + wv[2] * xv[2] + wv[3] * xv[3];
    }
  }
  #pragma unroll
  for (int oo = 0; oo < 4; ++oo)
    G[b * 1536 + r0 + rbase + oo] = acc[oo];
}

// -------- GRU gates -> rQ2 --------
__global__ __launch_bounds__(256) void k_gates(const float* __restrict__ gi,
                                               const float* __restrict__ gh,
                                               const float* __restrict__ ct,
                                               float* __restrict__ rQ2) {
  int idx = blockIdx.x * 256 + threadIdx.x;
  int b = idx >> 9;
  int j = idx & 511;
  const float* gib = gi + b * 1536;
  const float* ghb = gh + b * 1536;
  float r = 1.f / (1.f + expf(-(gib[j] + ghb[j])));
  float z = 1.f / (1.f + expf(-(gib[512 + j] + ghb[512 + j])));
  float n = tanhf(gib[1024 + j] + r * ghb[1024 + j]);
  rQ2[b * D2H + j] = (1.f - z) * n + z * ct[b * D2H + j];
}

// -------- u2[m][n] = Wah[n] . rQ2[m] + Wah_b[n], grid 64 --------
__global__ __launch_bounds__(256) void k_u2(const float* __restrict__ rQ2,
                                            const float* __restrict__ Wah,
                                            const float* __restrict__ Wah_b,
                                            float* __restrict__ u2) {
  int m = blockIdx.x, n = threadIdx.x;
  __shared__ float s_r[D2H];
  s_r[n]       = rQ2[m * D2H + n];
  s_r[n + 256] = rQ2[m * D2H + n + 256];
  __syncthreads();
  float acc = Wah_b[n];
  const float* wr = Wah + (size_t)n * 512;
  for (int k4 = 0; k4 < 128; ++k4) {
    f32x4 wv = *(const f32x4*)&wr[k4 * 4];
    f32x4 rv = *(const f32x4*)&s_r[k4 * 4];
    acc += wv[0] * rv[0] + wv[1] * rv[1] + wv[2] * rv[2] + wv[3] * rv[3];
  }
  u2[m * Hn + n] = acc;
}

extern "C" void kernel_launch(void* const* d_in, const int* in_sizes, int n_in,
                              void* d_out, int out_size, void* d_ws, size_t ws_size,
                              hipStream_t stream) {
  const float* passEnc  = (const float*)d_in[0];
  const float* quesEnc  = (const float*)d_in[1];
  const float* WQu_W    = (const float*)d_in[2];
  const float* WQu_b    = (const float*)d_in[3];
  const float* WQv_W    = (const float*)d_in[4];
  const float* WQv_b    = (const float*)d_in[5];
  const float* WPh_W    = (const float*)d_in[6];
  const float* WPh_b    = (const float*)d_in[7];
  const float* Wah_W    = (const float*)d_in[8];
  const float* Wah_b    = (const float*)d_in[9];
  const float* Vt1      = (const float*)d_in[10];
  const float* Vt2      = (const float*)d_in[11];
  const float* VQr      = (const float*)d_in[12];
  const float* gru_wih  = (const float*)d_in[13];
  const float* gru_whh  = (const float*)d_in[14];
  const float* gru_bih  = (const float*)d_in[15];
  const float* gru_bhh  = (const float*)d_in[16];
  float* out = (float*)d_out;

  float* ws = (float*)d_ws;
  float* v2    = ws;                    // 256
  float* rQ    = v2 + 256;              // 32768
  float* u1    = rQ + 32768;            // 16384
  float* u2    = u1 + 16384;            // 16384
  float* sP    = u2 + 16384;            // 131072
  float* ct    = sP + 131072;           // 32768
  float* gi    = ct + 32768;            // 98304
  float* gh    = gi + 98304;            // 98304
  float* rQ2   = gh + 98304;            // 32768
  float* sQ    = rQ2 + 32768;           // 4096
  short* wqu16 = (short*)(sQ + 4096);   // 131072 shorts
  short* wph16 = wqu16 + 131072;        // 131072 shorts
  short* pp16  = wph16 + 131072;        // 33554432 shorts (67MB)
  short* pe16  = pp16 + 33554432;       // 67108864 shorts (134MB)
  short* qe16  = pe16 + 67108864;       // 2097152 shorts (4MB)

  hipMemsetAsync(sQ, 0, Bn * LQn * sizeof(float), stream);
  hipMemsetAsync(sP, 0, Bn * LPn * sizeof(float), stream);
  hipMemsetAsync(ct, 0, Bn * D2H * sizeof(float), stream);

  k_wcvt<<<256, 256, 0, stream>>>(WQu_W, WPh_W, wqu16, wph16);
  k_acvt<<<2048, 256, 0, stream>>>(passEnc, quesEnc, pe16, qe16);
  k_v2<<<1, 256, 0, stream>>>(VQr, WQv_W, WQv_b, v2);

  // question path: GEMM + sQ epilogue (no pp store). 64 blocks (32 Mtiles x2)
  k_mfma<<<LQn * Bn / 64, 256, 0, stream>>>(
      qe16, wqu16, WQu_b, v2, Vt1, nullptr, sQ, 0, LQn);
  k_rq_u1<<<Bn, 256, 0, stream>>>(sQ, quesEnc, Wah_W, Wah_b, rQ, u1);

  // pointer step 1: pass GEMM + sP1 epilogue + bf16 passP store. 2048 blocks
  k_mfma<<<LPn * Bn / 64, 256, 0, stream>>>(
      pe16, wph16, WPh_b, u1, Vt2, pp16, sP, Hn, LPn);
  k_softmax<<<Bn, 256, 0, stream>>>(sP, out);  // aP1

  k_ct<<<dim3(Bn, 32), 256, 0, stream>>>(out, passEnc, ct);

  k_gih<<<192, 256, 0, stream>>>(rQ, ct, gru_wih, gru_whh, gru_bih, gru_bhh, gi, gh);
  k_gates<<<Bn * D2H / 256, 256, 0, stream>>>(gi, gh, ct, rQ2);
  k_u2<<<Bn, 256, 0, stream>>>(rQ2, Wah_W, Wah_b, u2);

  // pointer step 2: epilogue replay from bf16 passP
  hipMemsetAsync(sP, 0, Bn * LPn * sizeof(float), stream);
  k_sp2<<<LPn * Bn / 64, 256, 0, stream>>>(pp16, u2, Vt2, sP);
  k_softmax<<<Bn, 256, 0, stream>>>(sP, out + Bn * LPn);  // aP2
}

// Round 4
// 832.272 us; speedup vs baseline: 1.1081x; 1.0841x over previous
//
#include <hip/hip_runtime.h>
#include <math.h>

// AnswerPointerNetwork: H=256, B=64, LP=2048, LQ=64, fp32 in/out.
// R9: post-mortem R3: (a) read-side LDS swizzle was ~8-way bank-conflicted
// (2.5e7 conflict-cycles: 64 lanes -> 8 bank-groups); (b) (256,4) budget
// 64+64 regs -> epilogue spill (+254MB HBM write); (c) k_acvt made passEnc
// traffic 536MB vs 268MB direct.
// Fixes:
//  (1) Fragment-order LDS: each (16-row x 16B) fragment slab stored so a
//      ds_read_b128 is uniform_base + lane*16 (1KB contiguous per instr,
//      ZERO conflicts by construction). Inverse permutation applied to the
//      per-thread GLOBAL source address feeding async16 (LDS dest stays
//      lane-linear, as global_load_lds requires).
//  (2) A staged as fp32 planes (32KB) via async16 only — no k_acvt, no
//      staging VGPRs, cvt8 to bf16 at fragment-read (R6-style). B bf16 16KB.
//  (3) __launch_bounds__(256,3): 170-reg budget, no spill. LDS 48KB -> 3
//      blocks/CU anyway.
//  (4) pp16 wave-contiguous 1KB stores kept (R3's fix, clean 67MB).

constexpr int Bn   = 64;
constexpr int Hn   = 256;
constexpr int D2H  = 512;
constexpr int LPn  = 2048;
constexpr int LQn  = 64;

typedef __attribute__((ext_vector_type(8))) short bf16x8;
typedef __attribute__((ext_vector_type(4))) float f32x4;

typedef const __attribute__((address_space(1))) unsigned int* gup;
typedef __attribute__((address_space(3))) unsigned int* lup;
__device__ inline void async16(const void* g, void* l) {
  __builtin_amdgcn_global_load_lds((gup)g, (lup)l, 16, 0, 0);
}

__device__ inline float waveAllSum(float v) {
  #pragma unroll
  for (int o = 32; o > 0; o >>= 1) v += __shfl_xor(v, o, 64);
  return v;
}
__device__ inline float waveAllMax(float v) {
  #pragma unroll
  for (int o = 32; o > 0; o >>= 1) v = fmaxf(v, __shfl_xor(v, o, 64));
  return v;
}

__device__ inline short f2bf_rtne(float f) {
  union { float f; unsigned u; } v; v.f = f;
  unsigned r = v.u + 0x7FFF + ((v.u >> 16) & 1);
  return (short)(r >> 16);
}
__device__ inline unsigned pk2(float lo, float hi) {
  union { float f; unsigned u; } a, b; a.f = lo; b.f = hi;
  return __builtin_amdgcn_perm(b.u + 0x8000u, a.u + 0x8000u, 0x07060302u);
}
__device__ inline bf16x8 cvt8(f32x4 a0, f32x4 a1) {
  union { unsigned u[4]; bf16x8 v; } r;
  r.u[0] = pk2(a0[0], a0[1]);
  r.u[1] = pk2(a0[2], a0[3]);
  r.u[2] = pk2(a1[0], a1[1]);
  r.u[3] = pk2(a1[2], a1[3]);
  return r.v;
}

// -------- W -> plain row-major bf16 --------
__global__ __launch_bounds__(256) void k_wcvt(const float* __restrict__ WQu,
                                              const float* __restrict__ WPh,
                                              short* __restrict__ q16,
                                              short* __restrict__ p16) {
  int e = (blockIdx.x * 256 + threadIdx.x) * 4;
  const float* src; short* dst; int off;
  if (e < 131072) { src = WQu; dst = q16; off = e; }
  else            { src = WPh; dst = p16; off = e - 131072; }
  f32x4 f = *(const f32x4*)&src[off];
  short4 h;
  h.x = f2bf_rtne(f[0]); h.y = f2bf_rtne(f[1]);
  h.z = f2bf_rtne(f[2]); h.w = f2bf_rtne(f[3]);
  *(short4*)&dst[off] = h;
}

// -------- tiny: v2 = VQr @ WQv_W.T + WQv_b --------
__global__ __launch_bounds__(256) void k_v2(const float* __restrict__ VQr,
                                            const float* __restrict__ WQv_W,
                                            const float* __restrict__ WQv_b,
                                            float* __restrict__ v2) {
  __shared__ float s[256];
  int t = threadIdx.x;
  s[t] = VQr[t];
  __syncthreads();
  float acc = WQv_b[t];
  for (int k = 0; k < 256; ++k) acc += s[k] * WQv_W[t * 256 + k];
  v2[t] = acc;
}

// -------- fused MFMA GEMM + tanh-dot epilogue (fragment-order LDS) --------
// 1-D grid, 2 blocks per M-tile (N halves), partner pair 8 apart in linear
// id. Block: 128 rows x 128 cols, 4 waves (wave = 64x64).
//
// LDS fragment-order layout (per 64-K slab):
//  A (fp32, 32KB, 32 planes of 1KB): slot(R, fc) -> plane = (R>>4)*4 +
//    (fc>>3)*2 + (fc&1), inner = ((fc>>1)&3)*256 + (R&15)*16 bytes,
//    where fc = 16B chunk index (4 floats) in the row's 64-float slab.
//  B (bf16, 16KB, 16 planes): slot(R, c) -> plane = (R>>4)*2 + (c>>2),
//    inner = (c&3)*256 + (R&15)*16, c = 16B chunk (8 bf16).
//  Fragment read = plane*1024 + lane*16 -> fully contiguous, 0 conflicts.
__global__ __launch_bounds__(256, 3) void k_mfma(
    const float* __restrict__ A,     // [M][512] fp32
    const short* __restrict__ Wb,    // [256][512] bf16 row-major
    const float* __restrict__ bias,  // [256]
    const float* __restrict__ u,     // ustride=256: [64][256]; 0: [256]
    const float* __restrict__ vt,    // [64][256]
    short* __restrict__ pp,          // nullable: bf16 C store (wave-flat)
    float* __restrict__ sOut,        // [64][sstride], atomicAdd target
    int ustride, int sstride)
{
  __shared__ union {
    struct { float As[32 * 256]; short Bs[16 * 512]; } m;  // 32KB + 16KB
    float sred[256];
  } sm;
  const int t = threadIdx.x;
  const int w = t >> 6, l = t & 63, l15 = l & 15, quad = l >> 4;
  const int wm = w >> 1, wn = w & 1;
  // pair-swizzle: lin = grp*16 + half*8 + pairLocal
  const int lin   = blockIdx.x;
  const int grp   = lin >> 4;
  const int half  = (lin & 15) >> 3;
  const int mtile = grp * 8 + (lin & 7);
  const long bm = (long)mtile * 128;
  const int n0 = half * 128;

  f32x4 acc[4][4];
  #pragma unroll
  for (int i = 0; i < 4; ++i)
    #pragma unroll
    for (int j = 0; j < 4; ++j)
      acc[i][j] = (f32x4)0.f;

  // --- staging sources: inverse of the fragment-order layout ---
  // A: thread t, round it (0..7) fills LDS byte D = t*16 + it*4096.
  //    plane = (t>>6) + it*4 -> R = it*16 + (t&15),
  //    fc = (t>>7)*8 + ((t>>4)&3)*2 + ((t>>6)&1).
  const int fcA = ((t >> 7) << 3) | (((t >> 4) & 3) << 1) | ((t >> 6) & 1);
  const float* gA = A + (bm + (t & 15)) * 512 + fcA * 4;
  // B: round it (0..3), D = t*16 + it*4096. plane = (t>>6) + it*4 ->
  //    R = it*32 + (t>>7)*16 + (t&15), c = ((t>>6)&1)*4 + ((t>>4)&3).
  const int cB = (((t >> 6) & 1) << 2) | ((t >> 4) & 3);
  const short* gB = Wb + (size_t)(n0 + ((t >> 7) << 4) + (t & 15)) * 512 + cB * 8;
  char* lA = (char*)sm.m.As + t * 16;
  char* lB = (char*)sm.m.Bs + t * 16;

  for (int k0 = 0; k0 < 512; k0 += 64) {
    #pragma unroll
    for (int it = 0; it < 8; ++it)
      async16(gA + it * 8192 + k0, lA + it * 4096);    // 16 rows / round
    #pragma unroll
    for (int it = 0; it < 4; ++it)
      async16(gB + it * 16384 + k0, lB + it * 4096);   // 32 rows / round
    __syncthreads();
    const int lb = l * 4;   // f32 units within a plane
    #pragma unroll
    for (int ks = 0; ks < 2; ++ks) {
      bf16x8 af[4], bfv[4];
      #pragma unroll
      for (int i = 0; i < 4; ++i) {
        const int pl = ((wm * 4 + i) * 4 + ks * 2) * 256;   // f32 units
        f32x4 p0 = *(const f32x4*)&sm.m.As[pl + lb];
        f32x4 p1 = *(const f32x4*)&sm.m.As[pl + 256 + lb];
        af[i] = cvt8(p0, p1);
      }
      #pragma unroll
      for (int j = 0; j < 4; ++j) {
        const int rg = ((wn * 4 + j) * 2 + ks) * 512;       // short units
        bfv[j] = *(const bf16x8*)&sm.m.Bs[rg + l * 8];
      }
      #pragma unroll
      for (int i = 0; i < 4; ++i)
        #pragma unroll
        for (int j = 0; j < 4; ++j)
          acc[i][j] = __builtin_amdgcn_mfma_f32_16x16x32_bf16(af[i], bfv[j], acc[i][j], 0, 0, 0);
    }
    __syncthreads();
  }

  // epilogue: bias, optional bf16 C store (wave-contiguous layout), tanh-dot
  short* ppt = pp ? pp + (((size_t)mtile * 2 + half) * 16384 + (size_t)w * 4096 + l * 8)
                  : nullptr;
  float srow[4][4];
  #pragma unroll
  for (int i = 0; i < 4; ++i) {
    #pragma unroll
    for (int r = 0; r < 4; ++r) srow[i][r] = 0.f;
    unsigned pk[8];
    const int bb = i * 16 + quad * 4;
    #pragma unroll
    for (int j = 0; j < 4; ++j) {
      const int n = n0 + wn * 64 + j * 16 + l15;
      const float bn = bias[n];
      float v0 = acc[i][j][0] + bn, v1 = acc[i][j][1] + bn;
      float v2 = acc[i][j][2] + bn, v3 = acc[i][j][3] + bn;
      if (ppt) { pk[j * 2] = pk2(v0, v1); pk[j * 2 + 1] = pk2(v2, v3); }
      srow[i][0] += tanhf(v0 + u[ustride * (bb + 0) + n]) * vt[(bb + 0) * 256 + n];
      srow[i][1] += tanhf(v1 + u[ustride * (bb + 1) + n]) * vt[(bb + 1) * 256 + n];
      srow[i][2] += tanhf(v2 + u[ustride * (bb + 2) + n]) * vt[(bb + 2) * 256 + n];
      srow[i][3] += tanhf(v3 + u[ustride * (bb + 3) + n]) * vt[(bb + 3) * 256 + n];
    }
    if (ppt) {
      uint4 s0 = {pk[0], pk[1], pk[2], pk[3]};
      uint4 s1 = {pk[4], pk[5], pk[6], pk[7]};
      *(uint4*)&ppt[i * 1024]       = s0;   // 64 lanes x 16B contiguous
      *(uint4*)&ppt[i * 1024 + 512] = s1;
    }
  }
  #pragma unroll
  for (int off = 1; off < 16; off <<= 1)
    #pragma unroll
    for (int i = 0; i < 4; ++i)
      #pragma unroll
      for (int r = 0; r < 4; ++r)
        srow[i][r] += __shfl_xor(srow[i][r], off, 64);
  if (l15 == 0)
    #pragma unroll
    for (int i = 0; i < 4; ++i)
      #pragma unroll
      for (int r = 0; r < 4; ++r)
        sm.sred[wn * 128 + wm * 64 + i * 16 + quad * 4 + r] = srow[i][r];
  __syncthreads();
  if (t < 128) {
    float s = sm.sred[t] + sm.sred[128 + t];
    int b = t & 63;
    int pg = mtile * 2 + (t >> 6);
    atomicAdd(&sOut[(size_t)b * sstride + pg], s);
  }
}

// -------- pointer step 2: epilogue replay from bf16 passP --------
__global__ __launch_bounds__(256) void k_sp2(const short* __restrict__ pp,
                                             const float* __restrict__ u2,
                                             const float* __restrict__ vt,
                                             float* __restrict__ sP) {
  __shared__ float sred[256];
  const int g = blockIdx.x, t = threadIdx.x;
  const int w = t >> 6, l = t & 63, l15 = l & 15, quad = l >> 4;
  const int wm = w >> 1, wn = w & 1;
  const int n0 = (g & 1) * 128;
  const short* src = pp + (size_t)g * 16384 + (size_t)w * 4096 + l * 8;
  float srow[4][4];
  #pragma unroll
  for (int i = 0; i < 4; ++i) {
    uint4 q0 = *(const uint4*)&src[i * 1024];
    uint4 q1 = *(const uint4*)&src[i * 1024 + 512];
    unsigned pk[8] = {q0.x, q0.y, q0.z, q0.w, q1.x, q1.y, q1.z, q1.w};
    #pragma unroll
    for (int r = 0; r < 4; ++r) srow[i][r] = 0.f;
    const int bb = i * 16 + quad * 4;
    #pragma unroll
    for (int j = 0; j < 4; ++j) {
      const int n = n0 + wn * 64 + j * 16 + l15;
      #pragma unroll
      for (int r = 0; r < 4; ++r) {
        unsigned word = pk[j * 2 + (r >> 1)];
        unsigned bits = (r & 1) ? (word & 0xFFFF0000u) : (word << 16);
        float val = __uint_as_float(bits);
        srow[i][r] += tanhf(val + u2[(bb + r) * 256 + n]) * vt[(bb + r) * 256 + n];
      }
    }
  }
  #pragma unroll
  for (int off = 1; off < 16; off <<= 1)
    #pragma unroll
    for (int i = 0; i < 4; ++i)
      #pragma unroll
      for (int r = 0; r < 4; ++r)
        srow[i][r] += __shfl_xor(srow[i][r], off, 64);
  if (l15 == 0)
    #pragma unroll
    for (int i = 0; i < 4; ++i)
      #pragma unroll
      for (int r = 0; r < 4; ++r)
        sred[wn * 128 + wm * 64 + i * 16 + quad * 4 + r] = srow[i][r];
  __syncthreads();
  if (t < 128) {
    float s = sred[t] + sred[128 + t];
    int b = t & 63;
    int pg = (g >> 1) * 2 + (t >> 6);
    atomicAdd(&sP[(size_t)b * LPn + pg], s);
  }
}

// -------- softmax(sQ) -> rQ -> u1, one block per b --------
__global__ __launch_bounds__(256) void k_rq_u1(const float* __restrict__ sQ,
                                               const float* __restrict__ quesEnc,
                                               const float* __restrict__ Wah,
                                               const float* __restrict__ Wah_b,
                                               float* __restrict__ rQ,
                                               float* __restrict__ u1) {
  int b = blockIdx.x, tid = threadIdx.x;
  __shared__ float s_a[LQn];
  __shared__ float s_r[D2H];
  if (tid < 64) {
    float s = sQ[b * LQn + tid];
    float m = waveAllMax(s);
    float e = expf(s - m);
    float sum = waveAllSum(e);
    s_a[tid] = e / sum;
  }
  __syncthreads();
  #pragma unroll
  for (int rep = 0; rep < 2; ++rep) {
    int d = tid + rep * 256;
    float acc = 0.f;
    for (int q = 0; q < LQn; ++q)
      acc += s_a[q] * quesEnc[(size_t)(q * Bn + b) * D2H + d];
    s_r[d] = acc;
    rQ[b * D2H + d] = acc;
  }
  __syncthreads();
  float accu = Wah_b[tid];
  const float* wr = Wah + (size_t)tid * 512;
  for (int k4 = 0; k4 < 128; ++k4) {
    f32x4 wv = *(const f32x4*)&wr[k4 * 4];
    f32x4 rv = *(const f32x4*)&s_r[k4 * 4];
    accu += wv[0] * rv[0] + wv[1] * rv[1] + wv[2] * rv[2] + wv[3] * rv[3];
  }
  u1[b * Hn + tid] = accu;
}

// -------- softmax over 2048, one block per b --------
__global__ __launch_bounds__(256) void k_softmax(const float* __restrict__ sP,
                                                 float* __restrict__ out) {
  int b = blockIdx.x, tid = threadIdx.x;
  int lane = tid & 63, wid = tid >> 6;
  __shared__ float red[4];
  float v[8];
  float m = -1e30f;
  #pragma unroll
  for (int i = 0; i < 8; ++i) {
    v[i] = sP[b * LPn + i * 256 + tid];
    m = fmaxf(m, v[i]);
  }
  m = waveAllMax(m);
  if (lane == 0) red[wid] = m;
  __syncthreads();
  m = fmaxf(fmaxf(red[0], red[1]), fmaxf(red[2], red[3]));
  float s = 0.f;
  #pragma unroll
  for (int i = 0; i < 8; ++i) { v[i] = expf(v[i] - m); s += v[i]; }
  s = waveAllSum(s);
  __syncthreads();
  if (lane == 0) red[wid] = s;
  __syncthreads();
  s = red[0] + red[1] + red[2] + red[3];
  float inv = 1.0f / s;
  #pragma unroll
  for (int i = 0; i < 8; ++i) out[b * LPn + i * 256 + tid] = v[i] * inv;
}

// -------- ct[b][d] = sum_p aP[b][p]*passEnc[p,b,d], grid (64,32) --------
__global__ __launch_bounds__(256) void k_ct(const float* __restrict__ aP,
                                            const float* __restrict__ passEnc,
                                            float* __restrict__ ct) {
  int b = blockIdx.x, pc = blockIdx.y, tid = threadIdx.x;
  int dg = tid & 127;
  int pg = tid >> 7;
  f32x4 acc = (f32x4)0.f;
  #pragma unroll
  for (int pp = 0; pp < 32; ++pp) {
    int p = pc * 64 + pg * 32 + pp;
    float a = aP[b * LPn + p];
    acc += a * *(const f32x4*)&passEnc[((size_t)p * Bn + b) * D2H + dg * 4];
  }
  __shared__ f32x4 sacc[256];
  sacc[tid] = acc;
  __syncthreads();
  if (pg == 0) {
    acc += sacc[tid + 128];
    float* dst = &ct[b * D2H + dg * 4];
    atomicAdd(dst + 0, acc[0]);
    atomicAdd(dst + 1, acc[1]);
    atomicAdd(dst + 2, acc[2]);
    atomicAdd(dst + 3, acc[3]);
  }
}

// -------- GRU mat-vecs, weight-stationary: grid 192 --------
__global__ __launch_bounds__(256) void k_gih(const float* __restrict__ rQ,
                                             const float* __restrict__ ct,
                                             const float* __restrict__ wih,
                                             const float* __restrict__ whh,
                                             const float* __restrict__ bih,
                                             const float* __restrict__ bhh,
                                             float* __restrict__ gi,
                                             float* __restrict__ gh) {
  __shared__ float sw[16 * 512];
  int blk = blockIdx.x;
  bool isH = blk >= 96;
  const float* W = isH ? whh : wih;
  const float* X = isH ? ct : rQ;
  const float* bias = isH ? bhh : bih;
  float* G = isH ? gh : gi;
  int r0 = (isH ? blk - 96 : blk) * 16;
  int t = threadIdx.x;
  #pragma unroll
  for (int it = 0; it < 8; ++it) {
    int f4 = it * 256 + t;
    *(f32x4*)&sw[f4 * 4] = *(const f32x4*)&W[(size_t)r0 * 512 + f4 * 4];
  }
  __syncthreads();
  int b = t & 63;
  int rbase = (t >> 6) * 4;
  const float* x = X + b * 512;
  float acc[4];
  #pragma unroll
  for (int oo = 0; oo < 4; ++oo) acc[oo] = bias[r0 + rbase + oo];
  for (int k4 = 0; k4 < 128; ++k4) {
    f32x4 xv = *(const f32x4*)&x[k4 * 4];
    #pragma unroll
    for (int oo = 0; oo < 4; ++oo) {
      f32x4 wv = *(const f32x4*)&sw[(rbase + oo) * 512 + k4 * 4];
      acc[oo] += wv[0] * xv[0] + wv[1] * xv[1] + wv[2] * xv[2] + wv[3] * xv[3];
    }
  }
  #pragma unroll
  for (int oo = 0; oo < 4; ++oo)
    G[b * 1536 + r0 + rbase + oo] = acc[oo];
}

// -------- GRU gates -> rQ2 --------
__global__ __launch_bounds__(256) void k_gates(const float* __restrict__ gi,
                                               const float* __restrict__ gh,
                                               const float* __restrict__ ct,
                                               float* __restrict__ rQ2) {
  int idx = blockIdx.x * 256 + threadIdx.x;
  int b = idx >> 9;
  int j = idx & 511;
  const float* gib = gi + b * 1536;
  const float* ghb = gh + b * 1536;
  float r = 1.f / (1.f + expf(-(gib[j] + ghb[j])));
  float z = 1.f / (1.f + expf(-(gib[512 + j] + ghb[512 + j])));
  float n = tanhf(gib[1024 + j] + r * ghb[1024 + j]);
  rQ2[b * D2H + j] = (1.f - z) * n + z * ct[b * D2H + j];
}

// -------- u2[m][n] = Wah[n] . rQ2[m] + Wah_b[n], grid 64 --------
__global__ __launch_bounds__(256) void k_u2(const float* __restrict__ rQ2,
                                            const float* __restrict__ Wah,
                                            const float* __restrict__ Wah_b,
                                            float* __restrict__ u2) {
  int m = blockIdx.x, n = threadIdx.x;
  __shared__ float s_r[D2H];
  s_r[n]       = rQ2[m * D2H + n];
  s_r[n + 256] = rQ2[m * D2H + n + 256];
  __syncthreads();
  float acc = Wah_b[n];
  const float* wr = Wah + (size_t)n * 512;
  for (int k4 = 0; k4 < 128; ++k4) {
    f32x4 wv = *(const f32x4*)&wr[k4 * 4];
    f32x4 rv = *(const f32x4*)&s_r[k4 * 4];
    acc += wv[0] * rv[0] + wv[1] * rv[1] + wv[2] * rv[2] + wv[3] * rv[3];
  }
  u2[m * Hn + n] = acc;
}

extern "C" void kernel_launch(void* const* d_in, const int* in_sizes, int n_in,
                              void* d_out, int out_size, void* d_ws, size_t ws_size,
                              hipStream_t stream) {
  const float* passEnc  = (const float*)d_in[0];
  const float* quesEnc  = (const float*)d_in[1];
  const float* WQu_W    = (const float*)d_in[2];
  const float* WQu_b    = (const float*)d_in[3];
  const float* WQv_W    = (const float*)d_in[4];
  const float* WQv_b    = (const float*)d_in[5];
  const float* WPh_W    = (const float*)d_in[6];
  const float* WPh_b    = (const float*)d_in[7];
  const float* Wah_W    = (const float*)d_in[8];
  const float* Wah_b    = (const float*)d_in[9];
  const float* Vt1      = (const float*)d_in[10];
  const float* Vt2      = (const float*)d_in[11];
  const float* VQr      = (const float*)d_in[12];
  const float* gru_wih  = (const float*)d_in[13];
  const float* gru_whh  = (const float*)d_in[14];
  const float* gru_bih  = (const float*)d_in[15];
  const float* gru_bhh  = (const float*)d_in[16];
  float* out = (float*)d_out;

  float* ws = (float*)d_ws;
  float* v2    = ws;                    // 256
  float* rQ    = v2 + 256;              // 32768
  float* u1    = rQ + 32768;            // 16384
  float* u2    = u1 + 16384;            // 16384
  float* sP    = u2 + 16384;            // 131072
  float* ct    = sP + 131072;           // 32768
  float* gi    = ct + 32768;            // 98304
  float* gh    = gi + 98304;            // 98304
  float* rQ2   = gh + 98304;            // 32768
  float* sQ    = rQ2 + 32768;           // 4096
  short* wqu16 = (short*)(sQ + 4096);   // 131072 shorts
  short* wph16 = wqu16 + 131072;        // 131072 shorts
  short* pp16  = wph16 + 131072;        // 33554432 shorts (67MB)

  hipMemsetAsync(sQ, 0, Bn * LQn * sizeof(float), stream);
  hipMemsetAsync(sP, 0, Bn * LPn * sizeof(float), stream);
  hipMemsetAsync(ct, 0, Bn * D2H * sizeof(float), stream);

  k_wcvt<<<256, 256, 0, stream>>>(WQu_W, WPh_W, wqu16, wph16);
  k_v2<<<1, 256, 0, stream>>>(VQr, WQv_W, WQv_b, v2);

  // question path: GEMM + sQ epilogue (no pp store). 64 blocks (32 Mtiles x2)
  k_mfma<<<LQn * Bn / 64, 256, 0, stream>>>(
      quesEnc, wqu16, WQu_b, v2, Vt1, nullptr, sQ, 0, LQn);
  k_rq_u1<<<Bn, 256, 0, stream>>>(sQ, quesEnc, Wah_W, Wah_b, rQ, u1);

  // pointer step 1: pass GEMM + sP1 epilogue + bf16 passP store. 2048 blocks
  k_mfma<<<LPn * Bn / 64, 256, 0, stream>>>(
      passEnc, wph16, WPh_b, u1, Vt2, pp16, sP, Hn, LPn);
  k_softmax<<<Bn, 256, 0, stream>>>(sP, out);  // aP1

  k_ct<<<dim3(Bn, 32), 256, 0, stream>>>(out, passEnc, ct);

  k_gih<<<192, 256, 0, stream>>>(rQ, ct, gru_wih, gru_whh, gru_bih, gru_bhh, gi, gh);
  k_gates<<<Bn * D2H / 256, 256, 0, stream>>>(gi, gh, ct, rQ2);
  k_u2<<<Bn, 256, 0, stream>>>(rQ2, Wah_W, Wah_b, u2);

  // pointer step 2: epilogue replay from bf16 passP
  hipMemsetAsync(sP, 0, Bn * LPn * sizeof(float), stream);
  k_sp2<<<LPn * Bn / 64, 256, 0, stream>>>(pp16, u2, Vt2, sP);
  k_softmax<<<Bn, 256, 0, stream>>>(sP, out + Bn * LPn);  // aP2
}

// Round 5
// 767.650 us; speedup vs baseline: 1.2014x; 1.0842x over previous
//
#include <hip/hip_runtime.h>
#include <math.h>

// AnswerPointerNetwork: H=256, B=64, LP=2048, LQ=64, fp32 in/out.
// R10: post-mortem R4: time tracks occupancy/latency, NOT bank conflicts
// (R8 200us@occ41 vs R9 252us@occ30 with 1.5x conflicts). The serial
// stage->barrier(vmcnt0)->compute loop exposes full HBM latency at every
// barrier. Fix = T3-minimum 2-phase pipeline:
//  (1) Double-buffered LDS, BK=32: A fp32 16KB + B bf16 8KB per buffer,
//      48KB total -> 3 blocks/CU at __launch_bounds__(256,3).
//  (2) Issue slab t+1's async16 BEFORE computing slab t; single
//      __syncthreads per slab. The barrier's vmcnt(0) drain now lands
//      after ~300cy of MFMA/ds_read instead of right before compute.
//  (3) A stays fp32 via async16 (k_acvt was net-negative), R6-style
//      chunk-XOR LDS layout (best measured ~5cyc/op), cvt8 at frag read.
//  (4) Epilogue unchanged (wave-contiguous pp16). WRITE_SIZE is the
//      diagnostic for the constant ~140MB write excess.

constexpr int Bn   = 64;
constexpr int Hn   = 256;
constexpr int D2H  = 512;
constexpr int LPn  = 2048;
constexpr int LQn  = 64;

typedef __attribute__((ext_vector_type(8))) short bf16x8;
typedef __attribute__((ext_vector_type(4))) float f32x4;

typedef const __attribute__((address_space(1))) unsigned int* gup;
typedef __attribute__((address_space(3))) unsigned int* lup;
__device__ inline void async16(const void* g, void* l) {
  __builtin_amdgcn_global_load_lds((gup)g, (lup)l, 16, 0, 0);
}

__device__ inline float waveAllSum(float v) {
  #pragma unroll
  for (int o = 32; o > 0; o >>= 1) v += __shfl_xor(v, o, 64);
  return v;
}
__device__ inline float waveAllMax(float v) {
  #pragma unroll
  for (int o = 32; o > 0; o >>= 1) v = fmaxf(v, __shfl_xor(v, o, 64));
  return v;
}

__device__ inline short f2bf_rtne(float f) {
  union { float f; unsigned u; } v; v.f = f;
  unsigned r = v.u + 0x7FFF + ((v.u >> 16) & 1);
  return (short)(r >> 16);
}
__device__ inline unsigned pk2(float lo, float hi) {
  union { float f; unsigned u; } a, b; a.f = lo; b.f = hi;
  return __builtin_amdgcn_perm(b.u + 0x8000u, a.u + 0x8000u, 0x07060302u);
}
__device__ inline bf16x8 cvt8(f32x4 a0, f32x4 a1) {
  union { unsigned u[4]; bf16x8 v; } r;
  r.u[0] = pk2(a0[0], a0[1]);
  r.u[1] = pk2(a0[2], a0[3]);
  r.u[2] = pk2(a1[0], a1[1]);
  r.u[3] = pk2(a1[2], a1[3]);
  return r.v;
}

// -------- W -> plain row-major bf16 --------
__global__ __launch_bounds__(256) void k_wcvt(const float* __restrict__ WQu,
                                              const float* __restrict__ WPh,
                                              short* __restrict__ q16,
                                              short* __restrict__ p16) {
  int e = (blockIdx.x * 256 + threadIdx.x) * 4;
  const float* src; short* dst; int off;
  if (e < 131072) { src = WQu; dst = q16; off = e; }
  else            { src = WPh; dst = p16; off = e - 131072; }
  f32x4 f = *(const f32x4*)&src[off];
  short4 h;
  h.x = f2bf_rtne(f[0]); h.y = f2bf_rtne(f[1]);
  h.z = f2bf_rtne(f[2]); h.w = f2bf_rtne(f[3]);
  *(short4*)&dst[off] = h;
}

// -------- tiny: v2 = VQr @ WQv_W.T + WQv_b --------
__global__ __launch_bounds__(256) void k_v2(const float* __restrict__ VQr,
                                            const float* __restrict__ WQv_W,
                                            const float* __restrict__ WQv_b,
                                            float* __restrict__ v2) {
  __shared__ float s[256];
  int t = threadIdx.x;
  s[t] = VQr[t];
  __syncthreads();
  float acc = WQv_b[t];
  for (int k = 0; k < 256; ++k) acc += s[k] * WQv_W[t * 256 + k];
  v2[t] = acc;
}

// -------- fused MFMA GEMM + tanh-dot epilogue (2-phase dbuf pipeline) ----
// 1-D grid, 2 blocks per M-tile (N halves), partner pair 8 apart in linear
// id. Block: 128 rows x 128 cols, 4 waves (wave = 64x64). BK=32, 16 slabs.
//
// LDS per buffer: A fp32 [128 rows][32 K] chunk-XOR: slot(r, c: 8x16B) =
//   r*128B + (c^(r&7))*16B. B bf16 [128 rows][32 K]: slot(r, c: 4x16B) =
//   r*64B + (c^(r&3))*16B. Staging inverse applied to global src address.
__global__ __launch_bounds__(256, 3) void k_mfma(
    const float* __restrict__ A,     // [M][512] fp32
    const short* __restrict__ Wb,    // [256][512] bf16 row-major
    const float* __restrict__ bias,  // [256]
    const float* __restrict__ u,     // ustride=256: [64][256]; 0: [256]
    const float* __restrict__ vt,    // [64][256]
    short* __restrict__ pp,          // nullable: bf16 C store (wave-flat)
    float* __restrict__ sOut,        // [64][sstride], atomicAdd target
    int ustride, int sstride)
{
  __shared__ union {
    struct { float As[2][4096]; short Bs[2][4096]; } m;  // 32KB + 16KB
    float sred[256];
  } sm;
  const int t = threadIdx.x;
  const int w = t >> 6, l = t & 63, l15 = l & 15, quad = l >> 4;
  const int wm = w >> 1, wn = w & 1;
  const int lin   = blockIdx.x;
  const int grp   = lin >> 4;
  const int half  = (lin & 15) >> 3;
  const int mtile = grp * 8 + (lin & 7);
  const long bm = (long)mtile * 128;
  const int n0 = half * 128;

  f32x4 acc[4][4];
  #pragma unroll
  for (int i = 0; i < 4; ++i)
    #pragma unroll
    for (int j = 0; j < 4; ++j)
      acc[i][j] = (f32x4)0.f;

  // staging sources (inverse chunk-XOR). A: thread t, round it (0..3):
  //   LDS float f = it*1024 + t*4 -> row = it*32 + (t>>3), slot = t&7,
  //   c = (t&7)^((t>>3)&7). B: round it (0..1): LDS short s = it*2048+t*8
  //   -> row = it*64 + (t>>2), slot = t&3, c = (t&3)^((t>>2)&3).
  const float* gA = A + (bm + (t >> 3)) * 512 + (((t & 7) ^ ((t >> 3) & 7)) << 2);
  const short* gB = Wb + (size_t)(n0 + (t >> 2)) * 512 + (((t & 3) ^ ((t >> 2) & 3)) << 3);

  #define STAGE(buf, k0)                                                     \
    do {                                                                     \
      char* lA_ = (char*)&sm.m.As[buf][0] + t * 16;                          \
      char* lB_ = (char*)&sm.m.Bs[buf][0] + t * 16;                          \
      _Pragma("unroll")                                                      \
      for (int it = 0; it < 4; ++it)                                         \
        async16(gA + it * 16384 + (k0), lA_ + it * 4096);                    \
      _Pragma("unroll")                                                      \
      for (int it = 0; it < 2; ++it)                                         \
        async16(gB + it * 32768 + (k0), lB_ + it * 4096);                    \
    } while (0)

  STAGE(0, 0);
  __syncthreads();
  for (int s = 0; s < 16; ++s) {
    const int cur = s & 1;
    if (s < 15) STAGE(cur ^ 1, (s + 1) * 32);
    const float* As = &sm.m.As[cur][0];
    const short* Bs = &sm.m.Bs[cur][0];
    bf16x8 af[4], bfv[4];
    #pragma unroll
    for (int i = 0; i < 4; ++i) {
      const int R = wm * 64 + i * 16 + l15;     // R & 7 == l15 & 7
      const float* base = &As[R * 32];
      f32x4 p0 = *(const f32x4*)(base + (((quad * 2) ^ (l15 & 7)) << 2));
      f32x4 p1 = *(const f32x4*)(base + (((quad * 2 + 1) ^ (l15 & 7)) << 2));
      af[i] = cvt8(p0, p1);
    }
    #pragma unroll
    for (int j = 0; j < 4; ++j) {
      const int R = wn * 64 + j * 16 + l15;     // R & 3 == l15 & 3
      bfv[j] = *(const bf16x8*)&Bs[R * 32 + ((quad ^ (l15 & 3)) << 3)];
    }
    #pragma unroll
    for (int i = 0; i < 4; ++i)
      #pragma unroll
      for (int j = 0; j < 4; ++j)
        acc[i][j] = __builtin_amdgcn_mfma_f32_16x16x32_bf16(af[i], bfv[j], acc[i][j], 0, 0, 0);
    __syncthreads();   // vmcnt(0) drain overlapped by the compute above
  }
  #undef STAGE

  // epilogue: bias, optional bf16 C store (wave-contiguous layout), tanh-dot
  short* ppt = pp ? pp + (((size_t)mtile * 2 + half) * 16384 + (size_t)w * 4096 + l * 8)
                  : nullptr;
  float srow[4][4];
  #pragma unroll
  for (int i = 0; i < 4; ++i) {
    #pragma unroll
    for (int r = 0; r < 4; ++r) srow[i][r] = 0.f;
    unsigned pk[8];
    const int bb = i * 16 + quad * 4;
    #pragma unroll
    for (int j = 0; j < 4; ++j) {
      const int n = n0 + wn * 64 + j * 16 + l15;
      const float bn = bias[n];
      float v0 = acc[i][j][0] + bn, v1 = acc[i][j][1] + bn;
      float v2 = acc[i][j][2] + bn, v3 = acc[i][j][3] + bn;
      if (ppt) { pk[j * 2] = pk2(v0, v1); pk[j * 2 + 1] = pk2(v2, v3); }
      srow[i][0] += tanhf(v0 + u[ustride * (bb + 0) + n]) * vt[(bb + 0) * 256 + n];
      srow[i][1] += tanhf(v1 + u[ustride * (bb + 1) + n]) * vt[(bb + 1) * 256 + n];
      srow[i][2] += tanhf(v2 + u[ustride * (bb + 2) + n]) * vt[(bb + 2) * 256 + n];
      srow[i][3] += tanhf(v3 + u[ustride * (bb + 3) + n]) * vt[(bb + 3) * 256 + n];
    }
    if (ppt) {
      uint4 s0 = {pk[0], pk[1], pk[2], pk[3]};
      uint4 s1 = {pk[4], pk[5], pk[6], pk[7]};
      *(uint4*)&ppt[i * 1024]       = s0;   // 64 lanes x 16B contiguous
      *(uint4*)&ppt[i * 1024 + 512] = s1;
    }
  }
  #pragma unroll
  for (int off = 1; off < 16; off <<= 1)
    #pragma unroll
    for (int i = 0; i < 4; ++i)
      #pragma unroll
      for (int r = 0; r < 4; ++r)
        srow[i][r] += __shfl_xor(srow[i][r], off, 64);
  if (l15 == 0)
    #pragma unroll
    for (int i = 0; i < 4; ++i)
      #pragma unroll
      for (int r = 0; r < 4; ++r)
        sm.sred[wn * 128 + wm * 64 + i * 16 + quad * 4 + r] = srow[i][r];
  __syncthreads();
  if (t < 128) {
    float s = sm.sred[t] + sm.sred[128 + t];
    int b = t & 63;
    int pg = mtile * 2 + (t >> 6);
    atomicAdd(&sOut[(size_t)b * sstride + pg], s);
  }
}

// -------- pointer step 2: epilogue replay from bf16 passP --------
__global__ __launch_bounds__(256) void k_sp2(const short* __restrict__ pp,
                                             const float* __restrict__ u2,
                                             const float* __restrict__ vt,
                                             float* __restrict__ sP) {
  __shared__ float sred[256];
  const int g = blockIdx.x, t = threadIdx.x;
  const int w = t >> 6, l = t & 63, l15 = l & 15, quad = l >> 4;
  const int wm = w >> 1, wn = w & 1;
  const int n0 = (g & 1) * 128;
  const short* src = pp + (size_t)g * 16384 + (size_t)w * 4096 + l * 8;
  float srow[4][4];
  #pragma unroll
  for (int i = 0; i < 4; ++i) {
    uint4 q0 = *(const uint4*)&src[i * 1024];
    uint4 q1 = *(const uint4*)&src[i * 1024 + 512];
    unsigned pk[8] = {q0.x, q0.y, q0.z, q0.w, q1.x, q1.y, q1.z, q1.w};
    #pragma unroll
    for (int r = 0; r < 4; ++r) srow[i][r] = 0.f;
    const int bb = i * 16 + quad * 4;
    #pragma unroll
    for (int j = 0; j < 4; ++j) {
      const int n = n0 + wn * 64 + j * 16 + l15;
      #pragma unroll
      for (int r = 0; r < 4; ++r) {
        unsigned word = pk[j * 2 + (r >> 1)];
        unsigned bits = (r & 1) ? (word & 0xFFFF0000u) : (word << 16);
        float val = __uint_as_float(bits);
        srow[i][r] += tanhf(val + u2[(bb + r) * 256 + n]) * vt[(bb + r) * 256 + n];
      }
    }
  }
  #pragma unroll
  for (int off = 1; off < 16; off <<= 1)
    #pragma unroll
    for (int i = 0; i < 4; ++i)
      #pragma unroll
      for (int r = 0; r < 4; ++r)
        srow[i][r] += __shfl_xor(srow[i][r], off, 64);
  if (l15 == 0)
    #pragma unroll
    for (int i = 0; i < 4; ++i)
      #pragma unroll
      for (int r = 0; r < 4; ++r)
        sred[wn * 128 + wm * 64 + i * 16 + quad * 4 + r] = srow[i][r];
  __syncthreads();
  if (t < 128) {
    float s = sred[t] + sred[128 + t];
    int b = t & 63;
    int pg = (g >> 1) * 2 + (t >> 6);
    atomicAdd(&sP[(size_t)b * LPn + pg], s);
  }
}

// -------- softmax(sQ) -> rQ -> u1, one block per b --------
__global__ __launch_bounds__(256) void k_rq_u1(const float* __restrict__ sQ,
                                               const float* __restrict__ quesEnc,
                                               const float* __restrict__ Wah,
                                               const float* __restrict__ Wah_b,
                                               float* __restrict__ rQ,
                                               float* __restrict__ u1) {
  int b = blockIdx.x, tid = threadIdx.x;
  __shared__ float s_a[LQn];
  __shared__ float s_r[D2H];
  if (tid < 64) {
    float s = sQ[b * LQn + tid];
    float m = waveAllMax(s);
    float e = expf(s - m);
    float sum = waveAllSum(e);
    s_a[tid] = e / sum;
  }
  __syncthreads();
  #pragma unroll
  for (int rep = 0; rep < 2; ++rep) {
    int d = tid + rep * 256;
    float acc = 0.f;
    for (int q = 0; q < LQn; ++q)
      acc += s_a[q] * quesEnc[(size_t)(q * Bn + b) * D2H + d];
    s_r[d] = acc;
    rQ[b * D2H + d] = acc;
  }
  __syncthreads();
  float accu = Wah_b[tid];
  const float* wr = Wah + (size_t)tid * 512;
  for (int k4 = 0; k4 < 128; ++k4) {
    f32x4 wv = *(const f32x4*)&wr[k4 * 4];
    f32x4 rv = *(const f32x4*)&s_r[k4 * 4];
    accu += wv[0] * rv[0] + wv[1] * rv[1] + wv[2] * rv[2] + wv[3] * rv[3];
  }
  u1[b * Hn + tid] = accu;
}

// -------- softmax over 2048, one block per b --------
__global__ __launch_bounds__(256) void k_softmax(const float* __restrict__ sP,
                                                 float* __restrict__ out) {
  int b = blockIdx.x, tid = threadIdx.x;
  int lane = tid & 63, wid = tid >> 6;
  __shared__ float red[4];
  float v[8];
  float m = -1e30f;
  #pragma unroll
  for (int i = 0; i < 8; ++i) {
    v[i] = sP[b * LPn + i * 256 + tid];
    m = fmaxf(m, v[i]);
  }
  m = waveAllMax(m);
  if (lane == 0) red[wid] = m;
  __syncthreads();
  m = fmaxf(fmaxf(red[0], red[1]), fmaxf(red[2], red[3]));
  float s = 0.f;
  #pragma unroll
  for (int i = 0; i < 8; ++i) { v[i] = expf(v[i] - m); s += v[i]; }
  s = waveAllSum(s);
  __syncthreads();
  if (lane == 0) red[wid] = s;
  __syncthreads();
  s = red[0] + red[1] + red[2] + red[3];
  float inv = 1.0f / s;
  #pragma unroll
  for (int i = 0; i < 8; ++i) out[b * LPn + i * 256 + tid] = v[i] * inv;
}

// -------- ct[b][d] = sum_p aP[b][p]*passEnc[p,b,d], grid (64,32) --------
__global__ __launch_bounds__(256) void k_ct(const float* __restrict__ aP,
                                            const float* __restrict__ passEnc,
                                            float* __restrict__ ct) {
  int b = blockIdx.x, pc = blockIdx.y, tid = threadIdx.x;
  int dg = tid & 127;
  int pg = tid >> 7;
  f32x4 acc = (f32x4)0.f;
  #pragma unroll
  for (int pp = 0; pp < 32; ++pp) {
    int p = pc * 64 + pg * 32 + pp;
    float a = aP[b * LPn + p];
    acc += a * *(const f32x4*)&passEnc[((size_t)p * Bn + b) * D2H + dg * 4];
  }
  __shared__ f32x4 sacc[256];
  sacc[tid] = acc;
  __syncthreads();
  if (pg == 0) {
    acc += sacc[tid + 128];
    float* dst = &ct[b * D2H + dg * 4];
    atomicAdd(dst + 0, acc[0]);
    atomicAdd(dst + 1, acc[1]);
    atomicAdd(dst + 2, acc[2]);
    atomicAdd(dst + 3, acc[3]);
  }
}

// -------- GRU mat-vecs, weight-stationary: grid 192 --------
__global__ __launch_bounds__(256) void k_gih(const float* __restrict__ rQ,
                                             const float* __restrict__ ct,
                                             const float* __restrict__ wih,
                                             const float* __restrict__ whh,
                                             const float* __restrict__ bih,
                                             const float* __restrict__ bhh,
                                             float* __restrict__ gi,
                                             float* __restrict__ gh) {
  __shared__ float sw[16 * 512];
  int blk = blockIdx.x;
  bool isH = blk >= 96;
  const float* W = isH ? whh : wih;
  const float* X = isH ? ct : rQ;
  const float* bias = isH ? bhh : bih;
  float* G = isH ? gh : gi;
  int r0 = (isH ? blk - 96 : blk) * 16;
  int t = threadIdx.x;
  #pragma unroll
  for (int it = 0; it < 8; ++it) {
    int f4 = it * 256 + t;
    *(f32x4*)&sw[f4 * 4] = *(const f32x4*)&W[(size_t)r0 * 512 + f4 * 4];
  }
  __syncthreads();
  int b = t & 63;
  int rbase = (t >> 6) * 4;
  const float* x = X + b * 512;
  float acc[4];
  #pragma unroll
  for (int oo = 0; oo < 4; ++oo) acc[oo] = bias[r0 + rbase + oo];
  for (int k4 = 0; k4 < 128; ++k4) {
    f32x4 xv = *(const f32x4*)&x[k4 * 4];
    #pragma unroll
    for (int oo = 0; oo < 4; ++oo) {
      f32x4 wv = *(const f32x4*)&sw[(rbase + oo) * 512 + k4 * 4];
      acc[oo] += wv[0] * xv[0] + wv[1] * xv[1] + wv[2] * xv[2] + wv[3] * xv[3];
    }
  }
  #pragma unroll
  for (int oo = 0; oo < 4; ++oo)
    G[b * 1536 + r0 + rbase + oo] = acc[oo];
}

// -------- GRU gates -> rQ2 --------
__global__ __launch_bounds__(256) void k_gates(const float* __restrict__ gi,
                                               const float* __restrict__ gh,
                                               const float* __restrict__ ct,
                                               float* __restrict__ rQ2) {
  int idx = blockIdx.x * 256 + threadIdx.x;
  int b = idx >> 9;
  int j = idx & 511;
  const float* gib = gi + b * 1536;
  const float* ghb = gh + b * 1536;
  float r = 1.f / (1.f + expf(-(gib[j] + ghb[j])));
  float z = 1.f / (1.f + expf(-(gib[512 + j] + ghb[512 + j])));
  float n = tanhf(gib[1024 + j] + r * ghb[1024 + j]);
  rQ2[b * D2H + j] = (1.f - z) * n + z * ct[b * D2H + j];
}

// -------- u2[m][n] = Wah[n] . rQ2[m] + Wah_b[n], grid 64 --------
__global__ __launch_bounds__(256) void k_u2(const float* __restrict__ rQ2,
                                            const float* __restrict__ Wah,
                                            const float* __restrict__ Wah_b,
                                            float* __restrict__ u2) {
  int m = blockIdx.x, n = threadIdx.x;
  __shared__ float s_r[D2H];
  s_r[n]       = rQ2[m * D2H + n];
  s_r[n + 256] = rQ2[m * D2H + n + 256];
  __syncthreads();
  float acc = Wah_b[n];
  const float* wr = Wah + (size_t)n * 512;
  for (int k4 = 0; k4 < 128; ++k4) {
    f32x4 wv = *(const f32x4*)&wr[k4 * 4];
    f32x4 rv = *(const f32x4*)&s_r[k4 * 4];
    acc += wv[0] * rv[0] + wv[1] * rv[1] + wv[2] * rv[2] + wv[3] * rv[3];
  }
  u2[m * Hn + n] = acc;
}

extern "C" void kernel_launch(void* const* d_in, const int* in_sizes, int n_in,
                              void* d_out, int out_size, void* d_ws, size_t ws_size,
                              hipStream_t stream) {
  const float* passEnc  = (const float*)d_in[0];
  const float* quesEnc  = (const float*)d_in[1];
  const float* WQu_W    = (const float*)d_in[2];
  const float* WQu_b    = (const float*)d_in[3];
  const float* WQv_W    = (const float*)d_in[4];
  const float* WQv_b    = (const float*)d_in[5];
  const float* WPh_W    = (const float*)d_in[6];
  const float* WPh_b    = (const float*)d_in[7];
  const float* Wah_W    = (const float*)d_in[8];
  const float* Wah_b    = (const float*)d_in[9];
  const float* Vt1      = (const float*)d_in[10];
  const float* Vt2      = (const float*)d_in[11];
  const float* VQr      = (const float*)d_in[12];
  const float* gru_wih  = (const float*)d_in[13];
  const float* gru_whh  = (const float*)d_in[14];
  const float* gru_bih  = (const float*)d_in[15];
  const float* gru_bhh  = (const float*)d_in[16];
  float* out = (float*)d_out;

  float* ws = (float*)d_ws;
  float* v2    = ws;                    // 256
  float* rQ    = v2 + 256;              // 32768
  float* u1    = rQ + 32768;            // 16384
  float* u2    = u1 + 16384;            // 16384
  float* sP    = u2 + 16384;            // 131072
  float* ct    = sP + 131072;           // 32768
  float* gi    = ct + 32768;            // 98304
  float* gh    = gi + 98304;            // 98304
  float* rQ2   = gh + 98304;            // 32768
  float* sQ    = rQ2 + 32768;           // 4096
  short* wqu16 = (short*)(sQ + 4096);   // 131072 shorts
  short* wph16 = wqu16 + 131072;        // 131072 shorts
  short* pp16  = wph16 + 131072;        // 33554432 shorts (67MB)

  hipMemsetAsync(sQ, 0, Bn * LQn * sizeof(float), stream);
  hipMemsetAsync(sP, 0, Bn * LPn * sizeof(float), stream);
  hipMemsetAsync(ct, 0, Bn * D2H * sizeof(float), stream);

  k_wcvt<<<256, 256, 0, stream>>>(WQu_W, WPh_W, wqu16, wph16);
  k_v2<<<1, 256, 0, stream>>>(VQr, WQv_W, WQv_b, v2);

  // question path: GEMM + sQ epilogue (no pp store). 64 blocks (32 Mtiles x2)
  k_mfma<<<LQn * Bn / 64, 256, 0, stream>>>(
      quesEnc, wqu16, WQu_b, v2, Vt1, nullptr, sQ, 0, LQn);
  k_rq_u1<<<Bn, 256, 0, stream>>>(sQ, quesEnc, Wah_W, Wah_b, rQ, u1);

  // pointer step 1: pass GEMM + sP1 epilogue + bf16 passP store. 2048 blocks
  k_mfma<<<LPn * Bn / 64, 256, 0, stream>>>(
      passEnc, wph16, WPh_b, u1, Vt2, pp16, sP, Hn, LPn);
  k_softmax<<<Bn, 256, 0, stream>>>(sP, out);  // aP1

  k_ct<<<dim3(Bn, 32), 256, 0, stream>>>(out, passEnc, ct);

  k_gih<<<192, 256, 0, stream>>>(rQ, ct, gru_wih, gru_whh, gru_bih, gru_bhh, gi, gh);
  k_gates<<<Bn * D2H / 256, 256, 0, stream>>>(gi, gh, ct, rQ2);
  k_u2<<<Bn, 256, 0, stream>>>(rQ2, Wah_W, Wah_b, u2);

  // pointer step 2: epilogue replay from bf16 passP
  hipMemsetAsync(sP, 0, Bn * LPn * sizeof(float), stream);
  k_sp2<<<LPn * Bn / 64, 256, 0, stream>>>(pp16, u2, Vt2, sP);
  k_softmax<<<Bn, 256, 0, stream>>>(sP, out + Bn * LPn);  // aP2
}